// Round 3
// baseline (1195.343 us; speedup 1.0000x reference)
//
#include <hip/hip_runtime.h>

#define DEVINL __device__ __forceinline__

// Exact (no-FMA-contraction) squared distance in the same rounding order as
// numpy/jax fp32: ((dx*dx + dy*dy) + dz*dz). Discrete decisions (FPS argmax,
// ball-query radius compare) depend on bit-exactness.
DEVINL float sq3(float ax, float ay, float az, float bx, float by, float bz) {
  float dx = __fsub_rn(ax, bx), dy = __fsub_rn(ay, by), dz = __fsub_rn(az, bz);
  return __fadd_rn(__fadd_rn(__fmul_rn(dx, dx), __fmul_rn(dy, dy)), __fmul_rn(dz, dz));
}

// ---------------------------------------------------------------------------
// K0: one-off transpose of sa1_w2 [128][64] -> w2t [64][128] so k_sa1 can
// read per-d1 rows with contiguous scalar loads.
// ---------------------------------------------------------------------------
__global__ __launch_bounds__(256) void k_w2t(const float* __restrict__ w2,
                                             float* __restrict__ w2t) {
  const int i = blockIdx.x * 256 + threadIdx.x;
  if (i < 8192) {
    const int e = i >> 6, d = i & 63;
    w2t[d * 128 + e] = w2[i];
  }
}

// ---------------------------------------------------------------------------
// K1: farthest point sampling. One block per batch (32), 256 threads.
// Points cached in registers (8/thread). Per step: reg-resident min-update,
// packed-u64-key argmax (val<<32 | 2047-idx: u64 max == first-occurrence
// argmax), single barrier with parity-double-buffered cross-wave exchange,
// redundant final reduce in every thread (no serial phase).
// ---------------------------------------------------------------------------
__global__ __launch_bounds__(256) void k_fps(const float* __restrict__ xyz,
                                             int* __restrict__ fidx) {
  const int b = blockIdx.x, t = threadIdx.x;
  __shared__ float xs[2048], ys[2048], zs[2048];
  __shared__ unsigned long long skey[2][4];
  const float* P = xyz + (size_t)b * 6144;
  for (int i = t; i < 2048; i += 256) {
    xs[i] = P[3 * i]; ys[i] = P[3 * i + 1]; zs[i] = P[3 * i + 2];
  }
  __syncthreads();
  float px[8], py[8], pz[8], dist[8];
#pragma unroll
  for (int j = 0; j < 8; ++j) {
    const int idx = j * 256 + t;
    px[j] = xs[idx]; py[j] = ys[idx]; pz[j] = zs[idx];
    dist[j] = 1e10f;
  }
  int far = 0;
  int* out = fidx + b * 512;
  for (int it = 0; it < 512; ++it) {
    if (t == 0) out[it] = far;  // emit BEFORE update (scan emits carry's far)
    const float cx = xs[far], cy = ys[far], cz = zs[far];
    float bv = -1.0f;
    int bi = 0;
#pragma unroll
    for (int j = 0; j < 8; ++j) {
      const float d = sq3(px[j], py[j], pz[j], cx, cy, cz);
      const float nd = fminf(dist[j], d);
      dist[j] = nd;
      if (nd > bv) { bv = nd; bi = j * 256 + t; }  // strict >: smallest idx kept
    }
    // packed key: larger value wins; tie -> larger (2047-idx) -> smaller idx
    unsigned long long key =
        ((unsigned long long)__float_as_uint(bv) << 32) | (unsigned)(2047 - bi);
#pragma unroll
    for (int off = 1; off < 64; off <<= 1) {
      const unsigned hi = __shfl_xor((unsigned)(key >> 32), off);
      const unsigned lo = __shfl_xor((unsigned)key, off);
      const unsigned long long ok = ((unsigned long long)hi << 32) | lo;
      key = (ok > key) ? ok : key;
    }
    const int par = it & 1;
    if ((t & 63) == 0) skey[par][t >> 6] = key;
    __syncthreads();
    unsigned long long k0 = skey[par][0], k1 = skey[par][1];
    unsigned long long k2 = skey[par][2], k3 = skey[par][3];
    k0 = (k1 > k0) ? k1 : k0;
    k2 = (k3 > k2) ? k3 : k2;
    k0 = (k2 > k0) ? k2 : k0;
    far = 2047 - (int)((unsigned)k0 & 2047u);
  }
}

// ---------------------------------------------------------------------------
// K2: ball query. One wave per centroid (16384 waves). Collect first 32
// ascending indices with d2 <= r^2; pad with first hit. Also writes new_xyz.
// ---------------------------------------------------------------------------
__global__ __launch_bounds__(256) void k_ballq(const float* __restrict__ xyz,
                                               const int* __restrict__ fidx,
                                               float* __restrict__ new_xyz,
                                               int* __restrict__ gidx) {
  const int gw = (blockIdx.x * 256 + threadIdx.x) >> 6;  // centroid id
  const int lane = threadIdx.x & 63;
  const int b = gw >> 9;
  const float* P = xyz + (size_t)b * 6144;
  const int cidx = fidx[gw];
  const float cx = P[3 * cidx], cy = P[3 * cidx + 1], cz = P[3 * cidx + 2];
  if (lane < 3) new_xyz[(size_t)gw * 3 + lane] = P[3 * cidx + lane];
  int* g = gidx + (size_t)gw * 32;
  int base = 0, firstidx = -1;
  for (int c0 = 0; c0 < 2048; c0 += 64) {
    const int idx = c0 + lane;
    const float d = sq3(cx, cy, cz, P[3 * idx], P[3 * idx + 1], P[3 * idx + 2]);
    const bool in = !(d > 0.04f);  // matches: exclude where sqr > r*r
    const unsigned long long m = __ballot(in);
    if (firstidx < 0 && m) firstidx = c0 + (int)__builtin_ctzll(m);
    if (in) {
      const int pos = base + (int)__popcll(m & ((1ull << lane) - 1ull));
      if (pos < 32) g[pos] = idx;
    }
    base += (int)__popcll(m);
    if (base >= 32) break;  // wave-uniform
  }
  for (int pos = base + lane; pos < 32; pos += 64) g[pos] = firstidx;
}

// ---------------------------------------------------------------------------
// K3: SA1 fused MLP (3->64->64->128) + max over 32 samples/group.
// lane = one grouped point; h0[64] regs; streaming d1-loop accumulates
// layer2 into acc[128] regs (all reg indices compile-time).
// Weights are read from GLOBAL with wave-uniform addresses -> compiler emits
// s_load into SGPRs (scalar/constant-cache path), keeping the LDS pipe idle
// and v_fma consuming SGPR operands directly. (Round-2 profile showed the
// LDS weight-broadcast reads oversubscribed the LDS pipe ~6x: VALUBusy 30%.)
// Block = 256 threads = 8 groups. Grid = 2048.
// ---------------------------------------------------------------------------
__global__ __launch_bounds__(256, 2) void k_sa1(
    const float* __restrict__ xyz, const float* __restrict__ new_xyz,
    const int* __restrict__ gidx, const float* __restrict__ w0,
    const float* __restrict__ b0, const float* __restrict__ w1,
    const float* __restrict__ b1, const float* __restrict__ w2t,
    const float* __restrict__ b2, float* __restrict__ l1p) {
  const int t = threadIdx.x;
  const int p = blockIdx.x * 256 + t;  // global sample id
  const int g = p >> 5;                // group id = b*512+si
  const int b = p >> 14;
  const int lane = t & 63;
  const int src = gidx[p];
  const float* P = xyz + (size_t)b * 6144;
  const float nx = new_xyz[(size_t)g * 3], ny = new_xyz[(size_t)g * 3 + 1],
              nz = new_xyz[(size_t)g * 3 + 2];
  const float x = P[3 * src] - nx, y = P[3 * src + 1] - ny, z = P[3 * src + 2] - nz;
  float h0[64];
#pragma unroll
  for (int d = 0; d < 64; ++d) {
    h0[d] = fmaxf(0.0f, fmaf(w0[3 * d], x,
                             fmaf(w0[3 * d + 1], y, fmaf(w0[3 * d + 2], z, b0[d]))));
  }
  float acc[128];
#pragma unroll
  for (int e = 0; e < 128; ++e) acc[e] = b2[e];
  for (int d1 = 0; d1 < 64; ++d1) {  // layer1 scalar + layer2 rank-1 update
    const float* wr = w1 + (d1 << 6);
    float s0 = 0.f, s1 = 0.f, s2 = 0.f, s3 = 0.f;
#pragma unroll
    for (int c = 0; c < 64; c += 4) {
      s0 = fmaf(wr[c], h0[c], s0);
      s1 = fmaf(wr[c + 1], h0[c + 1], s1);
      s2 = fmaf(wr[c + 2], h0[c + 2], s2);
      s3 = fmaf(wr[c + 3], h0[c + 3], s3);
    }
    const float s = fmaxf(0.0f, b1[d1] + ((s0 + s1) + (s2 + s3)));
    const float* w2r = w2t + (d1 << 7);
#pragma unroll
    for (int e = 0; e < 128; ++e) acc[e] = fmaf(s, w2r[e], acc[e]);
  }
  // relu + max over each 32-lane half (one group) + predicated store
  float* outg = l1p + (size_t)g * 128;
#pragma unroll
  for (int e = 0; e < 128; ++e) {
    float v = fmaxf(0.0f, acc[e]);
    v = fmaxf(v, __shfl_xor(v, 1));
    v = fmaxf(v, __shfl_xor(v, 2));
    v = fmaxf(v, __shfl_xor(v, 4));
    v = fmaxf(v, __shfl_xor(v, 8));
    v = fmaxf(v, __shfl_xor(v, 16));
    if ((lane & 31) == (e & 31)) outg[e] = v;
  }
}

// ---------------------------------------------------------------------------
// SA2 layer kernels: lane = point (m), A row in registers, weights via
// wave-uniform global reads (scalar path). Outputs transposed [d][m].
// ---------------------------------------------------------------------------
__global__ __launch_bounds__(256, 3) void k_sa2_l0(
    const float* __restrict__ new_xyz, const float* __restrict__ l1p,
    const float* __restrict__ w0, const float* __restrict__ b0,
    float* __restrict__ h0t) {
  const int pb = blockIdx.x >> 2, ds = blockIdx.x & 3;
  const int t = threadIdx.x;
  const int d0 = ds * 32;
  const int m = pb * 256 + t;
  const float ax = new_xyz[(size_t)m * 3], ay = new_xyz[(size_t)m * 3 + 1],
              az = new_xyz[(size_t)m * 3 + 2];
  float4 av[32];
  const float4* lp = (const float4*)(l1p + (size_t)m * 128);
#pragma unroll
  for (int i = 0; i < 32; ++i) av[i] = lp[i];
  for (int dd = 0; dd < 32; ++dd) {
    const float* wr = w0 + (size_t)(d0 + dd) * 131;
    float s = fmaf(wr[0], ax, fmaf(wr[1], ay, fmaf(wr[2], az, b0[d0 + dd])));
    float s0 = 0.f, s1 = 0.f, s2 = 0.f, s3 = 0.f;
#pragma unroll
    for (int i = 0; i < 32; ++i) {
      s0 = fmaf(wr[3 + 4 * i], av[i].x, s0);
      s1 = fmaf(wr[4 + 4 * i], av[i].y, s1);
      s2 = fmaf(wr[5 + 4 * i], av[i].z, s2);
      s3 = fmaf(wr[6 + 4 * i], av[i].w, s3);
    }
    s += (s0 + s1) + (s2 + s3);
    h0t[(size_t)(d0 + dd) * 16384 + m] = fmaxf(0.0f, s);
  }
}

__global__ __launch_bounds__(256, 3) void k_sa2_l1(
    const float* __restrict__ h0t, const float* __restrict__ w1,
    const float* __restrict__ b1, float* __restrict__ h1t) {
  const int pb = blockIdx.x >> 2, ds = blockIdx.x & 3;
  const int t = threadIdx.x;
  const int d0 = ds * 32;
  const int m = pb * 256 + t;
  float a[128];
#pragma unroll
  for (int c = 0; c < 128; ++c) a[c] = h0t[(size_t)c * 16384 + m];
  for (int dd = 0; dd < 32; ++dd) {
    const float* wr = w1 + (size_t)(d0 + dd) * 128;
    float s0 = 0.f, s1 = 0.f, s2 = 0.f, s3 = 0.f;
#pragma unroll
    for (int i = 0; i < 32; ++i) {
      s0 = fmaf(wr[4 * i], a[4 * i], s0);
      s1 = fmaf(wr[4 * i + 1], a[4 * i + 1], s1);
      s2 = fmaf(wr[4 * i + 2], a[4 * i + 2], s2);
      s3 = fmaf(wr[4 * i + 3], a[4 * i + 3], s3);
    }
    h1t[(size_t)(d0 + dd) * 16384 + m] =
        fmaxf(0.0f, b1[d0 + dd] + ((s0 + s1) + (s2 + s3)));
  }
}

__global__ __launch_bounds__(256, 3) void k_sa2_l2max(
    const float* __restrict__ h1t, const float* __restrict__ w2,
    const float* __restrict__ b2, float* __restrict__ pmax) {
  const int pb = blockIdx.x >> 3, ds = blockIdx.x & 7;
  const int t = threadIdx.x;
  const int d0 = ds * 32;
  const int m = pb * 256 + t;
  const int b = m >> 9;
  const int wc = ((pb << 2) + (t >> 6)) & 7;  // wave-chunk within batch (0..7)
  const int lane = t & 63;
  float a[128];
#pragma unroll
  for (int c = 0; c < 128; ++c) a[c] = h1t[(size_t)c * 16384 + m];
  for (int dd = 0; dd < 32; ++dd) {
    const float* wr = w2 + (size_t)(d0 + dd) * 128;
    float s0 = 0.f, s1 = 0.f, s2 = 0.f, s3 = 0.f;
#pragma unroll
    for (int i = 0; i < 32; ++i) {
      s0 = fmaf(wr[4 * i], a[4 * i], s0);
      s1 = fmaf(wr[4 * i + 1], a[4 * i + 1], s1);
      s2 = fmaf(wr[4 * i + 2], a[4 * i + 2], s2);
      s3 = fmaf(wr[4 * i + 3], a[4 * i + 3], s3);
    }
    float v = fmaxf(0.0f, b2[d0 + dd] + ((s0 + s1) + (s2 + s3)));
    v = fmaxf(v, __shfl_xor(v, 1));
    v = fmaxf(v, __shfl_xor(v, 2));
    v = fmaxf(v, __shfl_xor(v, 4));
    v = fmaxf(v, __shfl_xor(v, 8));
    v = fmaxf(v, __shfl_xor(v, 16));
    v = fmaxf(v, __shfl_xor(v, 32));
    if (lane == 0) pmax[((size_t)(b << 3) + wc) * 256 + d0 + dd] = v;
  }
}

// ---------------------------------------------------------------------------
// K7: head. One block (1 wave) per batch. obj = max over 8 wave-partials,
// pose MLP + fusion MLP + two scalar heads.
// ---------------------------------------------------------------------------
__global__ __launch_bounds__(64) void k_head(
    const float* __restrict__ pmax, const float* __restrict__ grasp,
    const float* __restrict__ initp, const float* __restrict__ finalp,
    const int* __restrict__ surf, const float* __restrict__ embi,
    const float* __restrict__ embf, const float* __restrict__ pw0,
    const float* __restrict__ pb0, const float* __restrict__ pw1,
    const float* __restrict__ pb1, const float* __restrict__ pw2,
    const float* __restrict__ pb2, const float* __restrict__ fw0,
    const float* __restrict__ fb0, const float* __restrict__ fw1,
    const float* __restrict__ fb1, const float* __restrict__ osw,
    const float* __restrict__ osb, const float* __restrict__ ocw,
    const float* __restrict__ ocb, float* __restrict__ out) {
  __shared__ float obj[256], xb[37], A0[64], A1[128], A2[128], F0[128], HID[64];
  const int b = blockIdx.x, l = threadIdx.x;
  const float* pm = pmax + (size_t)b * 2048;
  for (int e = l; e < 256; e += 64) {
    float v = pm[e];
#pragma unroll
    for (int w = 1; w < 8; ++w) v = fmaxf(v, pm[w * 256 + e]);
    obj[e] = v;
  }
  if (l < 7) xb[l] = grasp[b * 7 + l];
  else if (l < 14) xb[l] = initp[b * 7 + l - 7];
  else if (l < 21) xb[l] = finalp[b * 7 + l - 14];
  else if (l < 29) xb[l] = embi[surf[b * 2] * 8 + l - 21];
  else if (l < 37) xb[l] = embf[surf[b * 2 + 1] * 8 + l - 29];
  __syncthreads();
  {
    float s = pb0[l];
    const float* wr = pw0 + l * 37;
#pragma unroll
    for (int c = 0; c < 37; ++c) s = fmaf(xb[c], wr[c], s);
    A0[l] = fmaxf(0.f, s);
  }
  __syncthreads();
#pragma unroll
  for (int dd = 0; dd < 2; ++dd) {
    const int d = l + dd * 64;
    float s = pb1[d];
    const float* wr = pw1 + d * 64;
#pragma unroll
    for (int c = 0; c < 64; ++c) s = fmaf(A0[c], wr[c], s);
    A1[d] = fmaxf(0.f, s);
  }
  __syncthreads();
#pragma unroll
  for (int dd = 0; dd < 2; ++dd) {
    const int d = l + dd * 64;
    float s = pb2[d];
    const float* wr = pw2 + d * 128;
#pragma unroll 16
    for (int c = 0; c < 128; ++c) s = fmaf(A1[c], wr[c], s);
    A2[d] = fmaxf(0.f, s);
  }
  __syncthreads();
#pragma unroll
  for (int dd = 0; dd < 2; ++dd) {
    const int d = l + dd * 64;
    float s = fb0[d];
    const float* wr = fw0 + d * 384;
#pragma unroll 16
    for (int c = 0; c < 256; ++c) s = fmaf(obj[c], wr[c], s);
#pragma unroll 16
    for (int c = 0; c < 128; ++c) s = fmaf(A2[c], wr[256 + c], s);
    F0[d] = fmaxf(0.f, s);
  }
  __syncthreads();
  {
    float s = fb1[l];
    const float* wr = fw1 + l * 128;
#pragma unroll 16
    for (int c = 0; c < 128; ++c) s = fmaf(F0[c], wr[c], s);
    HID[l] = fmaxf(0.f, s);
  }
  __syncthreads();
  float v1 = HID[l] * osw[l];
  float v2 = HID[l] * ocw[l];
#pragma unroll
  for (int off = 1; off < 64; off <<= 1) {
    v1 += __shfl_xor(v1, off);
    v2 += __shfl_xor(v2, off);
  }
  if (l == 0) {
    out[b] = v1 + osb[0];
    out[32 + b] = v2 + ocb[0];
  }
}

extern "C" void kernel_launch(void* const* d_in, const int* in_sizes, int n_in,
                              void* d_out, int out_size, void* d_ws, size_t ws_size,
                              hipStream_t stream) {
  const float* points  = (const float*)d_in[0];
  const float* grasp   = (const float*)d_in[1];
  const float* initp   = (const float*)d_in[2];
  const float* finalp  = (const float*)d_in[3];
  const int*   surf    = (const int*)d_in[4];
  const float* sa1_w0  = (const float*)d_in[5];
  const float* sa1_b0  = (const float*)d_in[6];
  const float* sa1_w1  = (const float*)d_in[7];
  const float* sa1_b1  = (const float*)d_in[8];
  const float* sa1_w2  = (const float*)d_in[9];
  const float* sa1_b2  = (const float*)d_in[10];
  const float* sa2_w0  = (const float*)d_in[11];
  const float* sa2_b0  = (const float*)d_in[12];
  const float* sa2_w1  = (const float*)d_in[13];
  const float* sa2_b1  = (const float*)d_in[14];
  const float* sa2_w2  = (const float*)d_in[15];
  const float* sa2_b2  = (const float*)d_in[16];
  const float* embi    = (const float*)d_in[17];
  const float* embf    = (const float*)d_in[18];
  const float* pe_w0   = (const float*)d_in[19];
  const float* pe_b0   = (const float*)d_in[20];
  const float* pe_w1   = (const float*)d_in[21];
  const float* pe_b1   = (const float*)d_in[22];
  const float* pe_w2   = (const float*)d_in[23];
  const float* pe_b2   = (const float*)d_in[24];
  const float* fu_w0   = (const float*)d_in[25];
  const float* fu_b0   = (const float*)d_in[26];
  const float* fu_w1   = (const float*)d_in[27];
  const float* fu_b1   = (const float*)d_in[28];
  const float* os_w    = (const float*)d_in[29];
  const float* os_b    = (const float*)d_in[30];
  const float* oc_w    = (const float*)d_in[31];
  const float* oc_b    = (const float*)d_in[32];

  char* ws = (char*)d_ws;
  // layout (bytes):
  int*   fidx    = (int*)(ws + 0);               //  65536
  float* new_xyz = (float*)(ws + 65536);         // 196608
  int*   gidx    = (int*)(ws + 262144);          // 2097152
  float* l1p     = (float*)(ws + 2359296);       // 8388608 (reused as h1t)
  float* h0t     = (float*)(ws + 10747904);      // 8388608
  float* pmax    = (float*)(ws + 19136512);      // 262144  -> end 19398656
  float* h1t     = l1p;   // l1_points dead after k_sa2_l0
  float* w2t     = h0t;   // w2t (32KB) lives in h0t region; k_sa1 reads it
                          // before k_sa2_l0 overwrites h0t (stream-ordered)

  float* out = (float*)d_out;

  k_w2t<<<32, 256, 0, stream>>>(sa1_w2, w2t);
  k_fps<<<32, 256, 0, stream>>>(points, fidx);
  k_ballq<<<4096, 256, 0, stream>>>(points, fidx, new_xyz, gidx);
  k_sa1<<<2048, 256, 0, stream>>>(points, new_xyz, gidx, sa1_w0, sa1_b0, sa1_w1,
                                  sa1_b1, w2t, sa1_b2, l1p);
  k_sa2_l0<<<256, 256, 0, stream>>>(new_xyz, l1p, sa2_w0, sa2_b0, h0t);
  k_sa2_l1<<<256, 256, 0, stream>>>(h0t, sa2_w1, sa2_b1, h1t);
  k_sa2_l2max<<<512, 256, 0, stream>>>(h1t, sa2_w2, sa2_b2, pmax);
  k_head<<<32, 64, 0, stream>>>(pmax, grasp, initp, finalp, surf, embi, embf,
                                pe_w0, pe_b0, pe_w1, pe_b1, pe_w2, pe_b2, fu_w0,
                                fu_b0, fu_w1, fu_b1, os_w, os_b, oc_w, oc_b, out);
}

// Round 4
// 941.133 us; speedup vs baseline: 1.2701x; 1.2701x over previous
//
#include <hip/hip_runtime.h>

#define DEVINL __device__ __forceinline__

// Exact (no-FMA-contraction) squared distance in the same rounding order as
// numpy/jax fp32: ((dx*dx + dy*dy) + dz*dz). Discrete decisions (FPS argmax,
// ball-query radius compare) depend on bit-exactness.
DEVINL float sq3(float ax, float ay, float az, float bx, float by, float bz) {
  float dx = __fsub_rn(ax, bx), dy = __fsub_rn(ay, by), dz = __fsub_rn(az, bz);
  return __fadd_rn(__fadd_rn(__fmul_rn(dx, dx), __fmul_rn(dy, dy)), __fmul_rn(dz, dz));
}

// ---------------------------------------------------------------------------
// K1: farthest point sampling. One block per batch (32), 256 threads.
// Points cached in registers (8/thread). Per step: reg-resident min-update,
// packed-u64-key argmax (val<<32 | 2047-idx: u64 max == first-occurrence
// argmax), single barrier with parity-double-buffered cross-wave exchange,
// redundant final reduce in every thread (no serial phase).
// ---------------------------------------------------------------------------
__global__ __launch_bounds__(256) void k_fps(const float* __restrict__ xyz,
                                             int* __restrict__ fidx) {
  const int b = blockIdx.x, t = threadIdx.x;
  __shared__ float xs[2048], ys[2048], zs[2048];
  __shared__ unsigned long long skey[2][4];
  const float* P = xyz + (size_t)b * 6144;
  for (int i = t; i < 2048; i += 256) {
    xs[i] = P[3 * i]; ys[i] = P[3 * i + 1]; zs[i] = P[3 * i + 2];
  }
  __syncthreads();
  float px[8], py[8], pz[8], dist[8];
#pragma unroll
  for (int j = 0; j < 8; ++j) {
    const int idx = j * 256 + t;
    px[j] = xs[idx]; py[j] = ys[idx]; pz[j] = zs[idx];
    dist[j] = 1e10f;
  }
  int far = 0;
  int* out = fidx + b * 512;
  for (int it = 0; it < 512; ++it) {
    if (t == 0) out[it] = far;  // emit BEFORE update (scan emits carry's far)
    const float cx = xs[far], cy = ys[far], cz = zs[far];
    float bv = -1.0f;
    int bi = 0;
#pragma unroll
    for (int j = 0; j < 8; ++j) {
      const float d = sq3(px[j], py[j], pz[j], cx, cy, cz);
      const float nd = fminf(dist[j], d);
      dist[j] = nd;
      if (nd > bv) { bv = nd; bi = j * 256 + t; }  // strict >: smallest idx kept
    }
    // packed key: larger value wins; tie -> larger (2047-idx) -> smaller idx
    unsigned long long key =
        ((unsigned long long)__float_as_uint(bv) << 32) | (unsigned)(2047 - bi);
#pragma unroll
    for (int off = 1; off < 64; off <<= 1) {
      const unsigned hi = __shfl_xor((unsigned)(key >> 32), off);
      const unsigned lo = __shfl_xor((unsigned)key, off);
      const unsigned long long ok = ((unsigned long long)hi << 32) | lo;
      key = (ok > key) ? ok : key;
    }
    const int par = it & 1;
    if ((t & 63) == 0) skey[par][t >> 6] = key;
    __syncthreads();
    unsigned long long k0 = skey[par][0], k1 = skey[par][1];
    unsigned long long k2 = skey[par][2], k3 = skey[par][3];
    k0 = (k1 > k0) ? k1 : k0;
    k2 = (k3 > k2) ? k3 : k2;
    k0 = (k2 > k0) ? k2 : k0;
    far = 2047 - (int)((unsigned)k0 & 2047u);
  }
}

// ---------------------------------------------------------------------------
// K2: ball query. One wave per centroid (16384 waves). Collect first 32
// ascending indices with d2 <= r^2; pad with first hit. Also writes new_xyz.
// ---------------------------------------------------------------------------
__global__ __launch_bounds__(256) void k_ballq(const float* __restrict__ xyz,
                                               const int* __restrict__ fidx,
                                               float* __restrict__ new_xyz,
                                               int* __restrict__ gidx) {
  const int gw = (blockIdx.x * 256 + threadIdx.x) >> 6;  // centroid id
  const int lane = threadIdx.x & 63;
  const int b = gw >> 9;
  const float* P = xyz + (size_t)b * 6144;
  const int cidx = fidx[gw];
  const float cx = P[3 * cidx], cy = P[3 * cidx + 1], cz = P[3 * cidx + 2];
  if (lane < 3) new_xyz[(size_t)gw * 3 + lane] = P[3 * cidx + lane];
  int* g = gidx + (size_t)gw * 32;
  int base = 0, firstidx = -1;
  for (int c0 = 0; c0 < 2048; c0 += 64) {
    const int idx = c0 + lane;
    const float d = sq3(cx, cy, cz, P[3 * idx], P[3 * idx + 1], P[3 * idx + 2]);
    const bool in = !(d > 0.04f);  // matches: exclude where sqr > r*r
    const unsigned long long m = __ballot(in);
    if (firstidx < 0 && m) firstidx = c0 + (int)__builtin_ctzll(m);
    if (in) {
      const int pos = base + (int)__popcll(m & ((1ull << lane) - 1ull));
      if (pos < 32) g[pos] = idx;
    }
    base += (int)__popcll(m);
    if (base >= 32) break;  // wave-uniform
  }
  for (int pos = base + lane; pos < 32; pos += 64) g[pos] = firstidx;
}

// ---------------------------------------------------------------------------
// K3: SA1 fused MLP (3->64->64->128) + max over 32 samples/group.
// lane = one grouped point. Restructured (round 4) to avoid the AGPR-bounce
// of a live acc[128]: compute layer-1 vector sv[64] in registers (h0 built in
// two 32-halves to keep the VGPR watermark ~110), then layer 2 as 128
// independent scalar dot-products over sv using the ORIGINAL w2 [e][c]
// layout (no transpose kernel). All weight reads are wave-uniform -> scalar
// s_load path; all register indices compile-time.
// Block = 256 threads = 8 groups. Grid = 2048.
// ---------------------------------------------------------------------------
__global__ __launch_bounds__(256, 2) void k_sa1(
    const float* __restrict__ xyz, const float* __restrict__ new_xyz,
    const int* __restrict__ gidx, const float* __restrict__ w0,
    const float* __restrict__ b0, const float* __restrict__ w1,
    const float* __restrict__ b1, const float* __restrict__ w2,
    const float* __restrict__ b2, float* __restrict__ l1p) {
  const int t = threadIdx.x;
  const int p = blockIdx.x * 256 + t;  // global sample id
  const int g = p >> 5;                // group id = b*512+si
  const int b = p >> 14;
  const int lane = t & 63;
  const int src = gidx[p];
  const float* P = xyz + (size_t)b * 6144;
  const float nx = new_xyz[(size_t)g * 3], ny = new_xyz[(size_t)g * 3 + 1],
              nz = new_xyz[(size_t)g * 3 + 2];
  const float x = P[3 * src] - nx, y = P[3 * src + 1] - ny, z = P[3 * src + 2] - nz;

  float sv[64];
#pragma unroll
  for (int d = 0; d < 64; ++d) sv[d] = b1[d];
#pragma unroll
  for (int half = 0; half < 2; ++half) {
    float h0[32];
#pragma unroll
    for (int d = 0; d < 32; ++d) {
      const int dd = half * 32 + d;
      h0[d] = fmaxf(0.0f, fmaf(w0[3 * dd], x,
                               fmaf(w0[3 * dd + 1], y,
                                    fmaf(w0[3 * dd + 2], z, b0[dd]))));
    }
#pragma unroll
    for (int d1 = 0; d1 < 64; ++d1) {
      const float* wr = w1 + (d1 << 6) + half * 32;
      float s0 = 0.f, s1 = 0.f, s2 = 0.f, s3 = 0.f;
#pragma unroll
      for (int c = 0; c < 32; c += 4) {
        s0 = fmaf(wr[c], h0[c], s0);
        s1 = fmaf(wr[c + 1], h0[c + 1], s1);
        s2 = fmaf(wr[c + 2], h0[c + 2], s2);
        s3 = fmaf(wr[c + 3], h0[c + 3], s3);
      }
      sv[d1] += (s0 + s1) + (s2 + s3);
    }
  }
#pragma unroll
  for (int d = 0; d < 64; ++d) sv[d] = fmaxf(0.0f, sv[d]);

  // layer 2: 128 scalar dots + relu + 32-lane max + predicated store
  float* outg = l1p + (size_t)g * 128;
#pragma unroll 2
  for (int e = 0; e < 128; ++e) {
    const float* wr = w2 + (e << 6);
    float s0 = 0.f, s1 = 0.f, s2 = 0.f, s3 = 0.f;
#pragma unroll
    for (int c = 0; c < 64; c += 4) {
      s0 = fmaf(wr[c], sv[c], s0);
      s1 = fmaf(wr[c + 1], sv[c + 1], s1);
      s2 = fmaf(wr[c + 2], sv[c + 2], s2);
      s3 = fmaf(wr[c + 3], sv[c + 3], s3);
    }
    float v = fmaxf(0.0f, b2[e] + ((s0 + s1) + (s2 + s3)));
    v = fmaxf(v, __shfl_xor(v, 1));
    v = fmaxf(v, __shfl_xor(v, 2));
    v = fmaxf(v, __shfl_xor(v, 4));
    v = fmaxf(v, __shfl_xor(v, 8));
    v = fmaxf(v, __shfl_xor(v, 16));
    if ((lane & 31) == (e & 31)) outg[e] = v;
  }
}

// ---------------------------------------------------------------------------
// SA2 layer kernels: lane = point (m), A row in registers, weights via
// wave-uniform global reads (scalar path). Outputs transposed [d][m].
// __launch_bounds__(256,2): bound 3 (round 3) capped VGPRs at ~170 and
// spilled the a[128] working set to scratch (-330 us regression).
// ---------------------------------------------------------------------------
__global__ __launch_bounds__(256, 2) void k_sa2_l0(
    const float* __restrict__ new_xyz, const float* __restrict__ l1p,
    const float* __restrict__ w0, const float* __restrict__ b0,
    float* __restrict__ h0t) {
  const int pb = blockIdx.x >> 2, ds = blockIdx.x & 3;
  const int t = threadIdx.x;
  const int d0 = ds * 32;
  const int m = pb * 256 + t;
  const float ax = new_xyz[(size_t)m * 3], ay = new_xyz[(size_t)m * 3 + 1],
              az = new_xyz[(size_t)m * 3 + 2];
  float4 av[32];
  const float4* lp = (const float4*)(l1p + (size_t)m * 128);
#pragma unroll
  for (int i = 0; i < 32; ++i) av[i] = lp[i];
  for (int dd = 0; dd < 32; ++dd) {
    const float* wr = w0 + (size_t)(d0 + dd) * 131;
    float s = fmaf(wr[0], ax, fmaf(wr[1], ay, fmaf(wr[2], az, b0[d0 + dd])));
    float s0 = 0.f, s1 = 0.f, s2 = 0.f, s3 = 0.f;
#pragma unroll
    for (int i = 0; i < 32; ++i) {
      s0 = fmaf(wr[3 + 4 * i], av[i].x, s0);
      s1 = fmaf(wr[4 + 4 * i], av[i].y, s1);
      s2 = fmaf(wr[5 + 4 * i], av[i].z, s2);
      s3 = fmaf(wr[6 + 4 * i], av[i].w, s3);
    }
    s += (s0 + s1) + (s2 + s3);
    h0t[(size_t)(d0 + dd) * 16384 + m] = fmaxf(0.0f, s);
  }
}

__global__ __launch_bounds__(256, 2) void k_sa2_l1(
    const float* __restrict__ h0t, const float* __restrict__ w1,
    const float* __restrict__ b1, float* __restrict__ h1t) {
  const int pb = blockIdx.x >> 2, ds = blockIdx.x & 3;
  const int t = threadIdx.x;
  const int d0 = ds * 32;
  const int m = pb * 256 + t;
  float a[128];
#pragma unroll
  for (int c = 0; c < 128; ++c) a[c] = h0t[(size_t)c * 16384 + m];
  for (int dd = 0; dd < 32; ++dd) {
    const float* wr = w1 + (size_t)(d0 + dd) * 128;
    float s0 = 0.f, s1 = 0.f, s2 = 0.f, s3 = 0.f;
#pragma unroll
    for (int i = 0; i < 32; ++i) {
      s0 = fmaf(wr[4 * i], a[4 * i], s0);
      s1 = fmaf(wr[4 * i + 1], a[4 * i + 1], s1);
      s2 = fmaf(wr[4 * i + 2], a[4 * i + 2], s2);
      s3 = fmaf(wr[4 * i + 3], a[4 * i + 3], s3);
    }
    h1t[(size_t)(d0 + dd) * 16384 + m] =
        fmaxf(0.0f, b1[d0 + dd] + ((s0 + s1) + (s2 + s3)));
  }
}

__global__ __launch_bounds__(256, 2) void k_sa2_l2max(
    const float* __restrict__ h1t, const float* __restrict__ w2,
    const float* __restrict__ b2, float* __restrict__ pmax) {
  const int pb = blockIdx.x >> 3, ds = blockIdx.x & 7;
  const int t = threadIdx.x;
  const int d0 = ds * 32;
  const int m = pb * 256 + t;
  const int b = m >> 9;
  const int wc = ((pb << 2) + (t >> 6)) & 7;  // wave-chunk within batch (0..7)
  const int lane = t & 63;
  float a[128];
#pragma unroll
  for (int c = 0; c < 128; ++c) a[c] = h1t[(size_t)c * 16384 + m];
  for (int dd = 0; dd < 32; ++dd) {
    const float* wr = w2 + (size_t)(d0 + dd) * 128;
    float s0 = 0.f, s1 = 0.f, s2 = 0.f, s3 = 0.f;
#pragma unroll
    for (int i = 0; i < 32; ++i) {
      s0 = fmaf(wr[4 * i], a[4 * i], s0);
      s1 = fmaf(wr[4 * i + 1], a[4 * i + 1], s1);
      s2 = fmaf(wr[4 * i + 2], a[4 * i + 2], s2);
      s3 = fmaf(wr[4 * i + 3], a[4 * i + 3], s3);
    }
    float v = fmaxf(0.0f, b2[d0 + dd] + ((s0 + s1) + (s2 + s3)));
    v = fmaxf(v, __shfl_xor(v, 1));
    v = fmaxf(v, __shfl_xor(v, 2));
    v = fmaxf(v, __shfl_xor(v, 4));
    v = fmaxf(v, __shfl_xor(v, 8));
    v = fmaxf(v, __shfl_xor(v, 16));
    v = fmaxf(v, __shfl_xor(v, 32));
    if (lane == 0) pmax[((size_t)(b << 3) + wc) * 256 + d0 + dd] = v;
  }
}

// ---------------------------------------------------------------------------
// K7: head. One block (1 wave) per batch. obj = max over 8 wave-partials,
// pose MLP + fusion MLP + two scalar heads.
// ---------------------------------------------------------------------------
__global__ __launch_bounds__(64) void k_head(
    const float* __restrict__ pmax, const float* __restrict__ grasp,
    const float* __restrict__ initp, const float* __restrict__ finalp,
    const int* __restrict__ surf, const float* __restrict__ embi,
    const float* __restrict__ embf, const float* __restrict__ pw0,
    const float* __restrict__ pb0, const float* __restrict__ pw1,
    const float* __restrict__ pb1, const float* __restrict__ pw2,
    const float* __restrict__ pb2, const float* __restrict__ fw0,
    const float* __restrict__ fb0, const float* __restrict__ fw1,
    const float* __restrict__ fb1, const float* __restrict__ osw,
    const float* __restrict__ osb, const float* __restrict__ ocw,
    const float* __restrict__ ocb, float* __restrict__ out) {
  __shared__ float obj[256], xb[37], A0[64], A1[128], A2[128], F0[128], HID[64];
  const int b = blockIdx.x, l = threadIdx.x;
  const float* pm = pmax + (size_t)b * 2048;
  for (int e = l; e < 256; e += 64) {
    float v = pm[e];
#pragma unroll
    for (int w = 1; w < 8; ++w) v = fmaxf(v, pm[w * 256 + e]);
    obj[e] = v;
  }
  if (l < 7) xb[l] = grasp[b * 7 + l];
  else if (l < 14) xb[l] = initp[b * 7 + l - 7];
  else if (l < 21) xb[l] = finalp[b * 7 + l - 14];
  else if (l < 29) xb[l] = embi[surf[b * 2] * 8 + l - 21];
  else if (l < 37) xb[l] = embf[surf[b * 2 + 1] * 8 + l - 29];
  __syncthreads();
  {
    float s = pb0[l];
    const float* wr = pw0 + l * 37;
#pragma unroll
    for (int c = 0; c < 37; ++c) s = fmaf(xb[c], wr[c], s);
    A0[l] = fmaxf(0.f, s);
  }
  __syncthreads();
#pragma unroll
  for (int dd = 0; dd < 2; ++dd) {
    const int d = l + dd * 64;
    float s = pb1[d];
    const float* wr = pw1 + d * 64;
#pragma unroll
    for (int c = 0; c < 64; ++c) s = fmaf(A0[c], wr[c], s);
    A1[d] = fmaxf(0.f, s);
  }
  __syncthreads();
#pragma unroll
  for (int dd = 0; dd < 2; ++dd) {
    const int d = l + dd * 64;
    float s = pb2[d];
    const float* wr = pw2 + d * 128;
#pragma unroll 16
    for (int c = 0; c < 128; ++c) s = fmaf(A1[c], wr[c], s);
    A2[d] = fmaxf(0.f, s);
  }
  __syncthreads();
#pragma unroll
  for (int dd = 0; dd < 2; ++dd) {
    const int d = l + dd * 64;
    float s = fb0[d];
    const float* wr = fw0 + d * 384;
#pragma unroll 16
    for (int c = 0; c < 256; ++c) s = fmaf(obj[c], wr[c], s);
#pragma unroll 16
    for (int c = 0; c < 128; ++c) s = fmaf(A2[c], wr[256 + c], s);
    F0[d] = fmaxf(0.f, s);
  }
  __syncthreads();
  {
    float s = fb1[l];
    const float* wr = fw1 + l * 128;
#pragma unroll 16
    for (int c = 0; c < 128; ++c) s = fmaf(F0[c], wr[c], s);
    HID[l] = fmaxf(0.f, s);
  }
  __syncthreads();
  float v1 = HID[l] * osw[l];
  float v2 = HID[l] * ocw[l];
#pragma unroll
  for (int off = 1; off < 64; off <<= 1) {
    v1 += __shfl_xor(v1, off);
    v2 += __shfl_xor(v2, off);
  }
  if (l == 0) {
    out[b] = v1 + osb[0];
    out[32 + b] = v2 + ocb[0];
  }
}

extern "C" void kernel_launch(void* const* d_in, const int* in_sizes, int n_in,
                              void* d_out, int out_size, void* d_ws, size_t ws_size,
                              hipStream_t stream) {
  const float* points  = (const float*)d_in[0];
  const float* grasp   = (const float*)d_in[1];
  const float* initp   = (const float*)d_in[2];
  const float* finalp  = (const float*)d_in[3];
  const int*   surf    = (const int*)d_in[4];
  const float* sa1_w0  = (const float*)d_in[5];
  const float* sa1_b0  = (const float*)d_in[6];
  const float* sa1_w1  = (const float*)d_in[7];
  const float* sa1_b1  = (const float*)d_in[8];
  const float* sa1_w2  = (const float*)d_in[9];
  const float* sa1_b2  = (const float*)d_in[10];
  const float* sa2_w0  = (const float*)d_in[11];
  const float* sa2_b0  = (const float*)d_in[12];
  const float* sa2_w1  = (const float*)d_in[13];
  const float* sa2_b1  = (const float*)d_in[14];
  const float* sa2_w2  = (const float*)d_in[15];
  const float* sa2_b2  = (const float*)d_in[16];
  const float* embi    = (const float*)d_in[17];
  const float* embf    = (const float*)d_in[18];
  const float* pe_w0   = (const float*)d_in[19];
  const float* pe_b0   = (const float*)d_in[20];
  const float* pe_w1   = (const float*)d_in[21];
  const float* pe_b1   = (const float*)d_in[22];
  const float* pe_w2   = (const float*)d_in[23];
  const float* pe_b2   = (const float*)d_in[24];
  const float* fu_w0   = (const float*)d_in[25];
  const float* fu_b0   = (const float*)d_in[26];
  const float* fu_w1   = (const float*)d_in[27];
  const float* fu_b1   = (const float*)d_in[28];
  const float* os_w    = (const float*)d_in[29];
  const float* os_b    = (const float*)d_in[30];
  const float* oc_w    = (const float*)d_in[31];
  const float* oc_b    = (const float*)d_in[32];

  char* ws = (char*)d_ws;
  // layout (bytes):
  int*   fidx    = (int*)(ws + 0);               //  65536
  float* new_xyz = (float*)(ws + 65536);         // 196608
  int*   gidx    = (int*)(ws + 262144);          // 2097152
  float* l1p     = (float*)(ws + 2359296);       // 8388608 (reused as h1t)
  float* h0t     = (float*)(ws + 10747904);      // 8388608
  float* pmax    = (float*)(ws + 19136512);      // 262144  -> end 19398656
  float* h1t     = l1p;   // l1_points dead after k_sa2_l0

  float* out = (float*)d_out;

  k_fps<<<32, 256, 0, stream>>>(points, fidx);
  k_ballq<<<4096, 256, 0, stream>>>(points, fidx, new_xyz, gidx);
  k_sa1<<<2048, 256, 0, stream>>>(points, new_xyz, gidx, sa1_w0, sa1_b0, sa1_w1,
                                  sa1_b1, sa1_w2, sa1_b2, l1p);
  k_sa2_l0<<<256, 256, 0, stream>>>(new_xyz, l1p, sa2_w0, sa2_b0, h0t);
  k_sa2_l1<<<256, 256, 0, stream>>>(h0t, sa2_w1, sa2_b1, h1t);
  k_sa2_l2max<<<512, 256, 0, stream>>>(h1t, sa2_w2, sa2_b2, pmax);
  k_head<<<32, 64, 0, stream>>>(pmax, grasp, initp, finalp, surf, embi, embf,
                                pe_w0, pe_b0, pe_w1, pe_b1, pe_w2, pe_b2, fu_w0,
                                fu_b0, fu_w1, fu_b1, os_w, os_b, oc_w, oc_b, out);
}

// Round 5
// 719.289 us; speedup vs baseline: 1.6618x; 1.3084x over previous
//
#include <hip/hip_runtime.h>

#define DEVINL __device__ __forceinline__

// Exact (no-FMA-contraction) squared distance in the same rounding order as
// numpy/jax fp32: ((dx*dx + dy*dy) + dz*dz). Discrete decisions (FPS argmax,
// ball-query radius compare) depend on bit-exactness.
DEVINL float sq3(float ax, float ay, float az, float bx, float by, float bz) {
  float dx = __fsub_rn(ax, bx), dy = __fsub_rn(ay, by), dz = __fsub_rn(az, bz);
  return __fadd_rn(__fadd_rn(__fmul_rn(dx, dx), __fmul_rn(dy, dy)), __fmul_rn(dz, dz));
}

// DPP max-trees (VALU pipe; __shfl_xor lowers to LDS-pipe ops). All reduced
// values are >= 0 and old=own, so invalid-lane semantics (0 or old) are both
// identity-safe. row_shr:1/2/4/8 + row_bcast:15 -> 32-lane max at lanes 31/63;
// + row_bcast:31 -> 64-lane max at lane 63.
template <int CTRL>
DEVINL float dpp_maxf(float v) {
  int o = __builtin_amdgcn_update_dpp(__float_as_int(v), __float_as_int(v),
                                      CTRL, 0xf, 0xf, false);
  return fmaxf(v, __int_as_float(o));
}
template <int CTRL>
DEVINL unsigned dpp_maxu(unsigned v) {
  unsigned o = (unsigned)__builtin_amdgcn_update_dpp((int)v, (int)v, CTRL, 0xf,
                                                     0xf, false);
  return (o > v) ? o : v;
}
DEVINL float red32_maxf(float v) {  // 32-lane group max -> valid at lanes 31,63
  v = dpp_maxf<0x111>(v); v = dpp_maxf<0x112>(v); v = dpp_maxf<0x114>(v);
  v = dpp_maxf<0x118>(v); v = dpp_maxf<0x142>(v);
  return v;
}
DEVINL float red64_maxf(float v) {  // 64-lane max -> valid at lane 63
  v = red32_maxf(v); v = dpp_maxf<0x143>(v);
  return v;
}
DEVINL unsigned red64_maxu(unsigned v) {
  v = dpp_maxu<0x111>(v); v = dpp_maxu<0x112>(v); v = dpp_maxu<0x114>(v);
  v = dpp_maxu<0x118>(v); v = dpp_maxu<0x142>(v); v = dpp_maxu<0x143>(v);
  return v;
}

// ---------------------------------------------------------------------------
// K1: farthest point sampling. One block per batch (32), 256 threads, points
// cached in registers (8/thread). Per step: reg min-update + bv max; 64-lane
// DPP float-max tree -> maxv; re-derive smallest tied index via rev=2047-idx
// DPP u32-max tree; single barrier for the 4-wave combine (packed u64 keys).
// Exact first-occurrence argmax semantics preserved bitwise.
// ---------------------------------------------------------------------------
__global__ __launch_bounds__(256) void k_fps(const float* __restrict__ xyz,
                                             int* __restrict__ fidx) {
  const int b = blockIdx.x, t = threadIdx.x;
  __shared__ float xs[2048], ys[2048], zs[2048];
  __shared__ unsigned long long skey[2][4];
  const float* P = xyz + (size_t)b * 6144;
  for (int i = t; i < 2048; i += 256) {
    xs[i] = P[3 * i]; ys[i] = P[3 * i + 1]; zs[i] = P[3 * i + 2];
  }
  __syncthreads();
  float px[8], py[8], pz[8], dist[8];
#pragma unroll
  for (int j = 0; j < 8; ++j) {
    const int idx = j * 256 + t;
    px[j] = xs[idx]; py[j] = ys[idx]; pz[j] = zs[idx];
    dist[j] = 1e10f;
  }
  int far = 0;
  int* out = fidx + b * 512;
  for (int it = 0; it < 512; ++it) {
    if (t == 0) out[it] = far;  // emit BEFORE update (scan emits carry's far)
    const float cx = xs[far], cy = ys[far], cz = zs[far];
    float bv = -1.0f;
#pragma unroll
    for (int j = 0; j < 8; ++j) {
      const float d = sq3(px[j], py[j], pz[j], cx, cy, cz);
      const float nd = fminf(dist[j], d);
      dist[j] = nd;
      bv = fmaxf(bv, nd);
    }
    const float tv = red64_maxf(bv);  // wave max (>=0)
    const float maxv =
        __int_as_float(__builtin_amdgcn_readlane(__float_as_int(tv), 63));
    unsigned rev = 0;  // 2047 - idx of tied entries; max rev == min idx
#pragma unroll
    for (int j = 0; j < 8; ++j) {
      if (dist[j] == maxv) {
        const unsigned r = 2047u - (unsigned)(j * 256 + t);
        rev = (r > rev) ? r : rev;
      }
    }
    rev = red64_maxu(rev);
    const int par = it & 1;
    if ((t & 63) == 63)
      skey[par][t >> 6] =
          ((unsigned long long)__float_as_uint(maxv) << 32) | rev;
    __syncthreads();
    unsigned long long k0 = skey[par][0], k1 = skey[par][1];
    unsigned long long k2 = skey[par][2], k3 = skey[par][3];
    k0 = (k1 > k0) ? k1 : k0;
    k2 = (k3 > k2) ? k3 : k2;
    k0 = (k2 > k0) ? k2 : k0;
    far = 2047 - (int)((unsigned)k0 & 2047u);
  }
}

// ---------------------------------------------------------------------------
// K2: ball query. One wave per centroid (16384 waves). Collect first 32
// ascending indices with d2 <= r^2; pad with first hit. Also writes new_xyz.
// ---------------------------------------------------------------------------
__global__ __launch_bounds__(256) void k_ballq(const float* __restrict__ xyz,
                                               const int* __restrict__ fidx,
                                               float* __restrict__ new_xyz,
                                               int* __restrict__ gidx) {
  const int gw = (blockIdx.x * 256 + threadIdx.x) >> 6;  // centroid id
  const int lane = threadIdx.x & 63;
  const int b = gw >> 9;
  const float* P = xyz + (size_t)b * 6144;
  const int cidx = fidx[gw];
  const float cx = P[3 * cidx], cy = P[3 * cidx + 1], cz = P[3 * cidx + 2];
  if (lane < 3) new_xyz[(size_t)gw * 3 + lane] = P[3 * cidx + lane];
  int* g = gidx + (size_t)gw * 32;
  int base = 0, firstidx = -1;
  for (int c0 = 0; c0 < 2048; c0 += 64) {
    const int idx = c0 + lane;
    const float d = sq3(cx, cy, cz, P[3 * idx], P[3 * idx + 1], P[3 * idx + 2]);
    const bool in = !(d > 0.04f);  // matches: exclude where sqr > r*r
    const unsigned long long m = __ballot(in);
    if (firstidx < 0 && m) firstidx = c0 + (int)__builtin_ctzll(m);
    if (in) {
      const int pos = base + (int)__popcll(m & ((1ull << lane) - 1ull));
      if (pos < 32) g[pos] = idx;
    }
    base += (int)__popcll(m);
    if (base >= 32) break;  // wave-uniform
  }
  for (int pos = base + lane; pos < 32; pos += 64) g[pos] = firstidx;
}

// ---------------------------------------------------------------------------
// SA1 split (round 5): kA = layers 0+1 -> svT staged in workspace (transposed
// float4 [d1/4][sample]); kB = layer 2 + 32-lane group max. Both kernels have
// ~75-85 reg watermark (below the 128/4-wave cap) to avoid the AGPR/scratch
// allocator pathology seen in the fused version (VGPR=56, 2x VALU ops).
// Weights stay on the wave-uniform scalar path.
// ---------------------------------------------------------------------------
__global__ __launch_bounds__(256, 4) void k_sa1a(
    const float* __restrict__ xyz, const float* __restrict__ new_xyz,
    const int* __restrict__ gidx, const float* __restrict__ w0,
    const float* __restrict__ b0, const float* __restrict__ w1,
    const float* __restrict__ b1, float4* __restrict__ svT, int p0, int SC) {
  const int q = blockIdx.x * 256 + threadIdx.x;  // chunk-local sample
  const int p = p0 + q;                          // global sample id
  const int g = p >> 5;
  const int b = p >> 14;
  const int src = gidx[p];
  const float* P = xyz + (size_t)b * 6144;
  const float nx = new_xyz[(size_t)g * 3], ny = new_xyz[(size_t)g * 3 + 1],
              nz = new_xyz[(size_t)g * 3 + 2];
  const float x = P[3 * src] - nx, y = P[3 * src + 1] - ny,
              z = P[3 * src + 2] - nz;
  float h0[64];
#pragma unroll
  for (int d = 0; d < 64; ++d) {
    h0[d] = fmaxf(0.0f, fmaf(w0[3 * d], x,
                             fmaf(w0[3 * d + 1], y,
                                  fmaf(w0[3 * d + 2], z, b0[d]))));
  }
  for (int d4 = 0; d4 < 16; ++d4) {
    float o[4];
#pragma unroll
    for (int k = 0; k < 4; ++k) {
      const int d1 = 4 * d4 + k;
      const float* wr = w1 + (d1 << 6);
      float s0 = 0.f, s1 = 0.f, s2 = 0.f, s3 = 0.f;
#pragma unroll
      for (int c = 0; c < 64; c += 4) {
        s0 = fmaf(wr[c], h0[c], s0);
        s1 = fmaf(wr[c + 1], h0[c + 1], s1);
        s2 = fmaf(wr[c + 2], h0[c + 2], s2);
        s3 = fmaf(wr[c + 3], h0[c + 3], s3);
      }
      o[k] = fmaxf(0.0f, b1[d1] + ((s0 + s1) + (s2 + s3)));
    }
    svT[(size_t)d4 * SC + q] = make_float4(o[0], o[1], o[2], o[3]);
  }
}

__global__ __launch_bounds__(256, 4) void k_sa1b(
    const float4* __restrict__ svT, const float* __restrict__ w2,
    const float* __restrict__ b2, float* __restrict__ l1p, int p0, int SC) {
  const int q = blockIdx.x * 256 + threadIdx.x;
  const int p = p0 + q;
  const int g = p >> 5;
  const int lane = threadIdx.x & 63;
  float sv[64];
#pragma unroll
  for (int i = 0; i < 16; ++i) {
    const float4 f = svT[(size_t)i * SC + q];
    sv[4 * i] = f.x; sv[4 * i + 1] = f.y; sv[4 * i + 2] = f.z;
    sv[4 * i + 3] = f.w;
  }
  float* outg = l1p + (size_t)g * 128;
  for (int e = 0; e < 128; ++e) {
    const float* wr = w2 + (e << 6);
    float s0 = 0.f, s1 = 0.f, s2 = 0.f, s3 = 0.f;
#pragma unroll
    for (int c = 0; c < 64; c += 4) {
      s0 = fmaf(wr[c], sv[c], s0);
      s1 = fmaf(wr[c + 1], sv[c + 1], s1);
      s2 = fmaf(wr[c + 2], sv[c + 2], s2);
      s3 = fmaf(wr[c + 3], sv[c + 3], s3);
    }
    float v = fmaxf(0.0f, b2[e] + ((s0 + s1) + (s2 + s3)));
    v = red32_maxf(v);  // group max, valid at lanes 31 & 63
    if ((lane & 31) == 31) outg[e] = v;
  }
}

// Fused fallback (round-4 kernel) if ws_size can't hold svT.
__global__ __launch_bounds__(256, 2) void k_sa1_fused(
    const float* __restrict__ xyz, const float* __restrict__ new_xyz,
    const int* __restrict__ gidx, const float* __restrict__ w0,
    const float* __restrict__ b0, const float* __restrict__ w1,
    const float* __restrict__ b1, const float* __restrict__ w2,
    const float* __restrict__ b2, float* __restrict__ l1p) {
  const int t = threadIdx.x;
  const int p = blockIdx.x * 256 + t;
  const int g = p >> 5;
  const int b = p >> 14;
  const int lane = t & 63;
  const int src = gidx[p];
  const float* P = xyz + (size_t)b * 6144;
  const float nx = new_xyz[(size_t)g * 3], ny = new_xyz[(size_t)g * 3 + 1],
              nz = new_xyz[(size_t)g * 3 + 2];
  const float x = P[3 * src] - nx, y = P[3 * src + 1] - ny,
              z = P[3 * src + 2] - nz;
  float sv[64];
#pragma unroll
  for (int d = 0; d < 64; ++d) sv[d] = b1[d];
#pragma unroll
  for (int half = 0; half < 2; ++half) {
    float h0[32];
#pragma unroll
    for (int d = 0; d < 32; ++d) {
      const int dd = half * 32 + d;
      h0[d] = fmaxf(0.0f, fmaf(w0[3 * dd], x,
                               fmaf(w0[3 * dd + 1], y,
                                    fmaf(w0[3 * dd + 2], z, b0[dd]))));
    }
#pragma unroll
    for (int d1 = 0; d1 < 64; ++d1) {
      const float* wr = w1 + (d1 << 6) + half * 32;
      float s0 = 0.f, s1 = 0.f, s2 = 0.f, s3 = 0.f;
#pragma unroll
      for (int c = 0; c < 32; c += 4) {
        s0 = fmaf(wr[c], h0[c], s0);
        s1 = fmaf(wr[c + 1], h0[c + 1], s1);
        s2 = fmaf(wr[c + 2], h0[c + 2], s2);
        s3 = fmaf(wr[c + 3], h0[c + 3], s3);
      }
      sv[d1] += (s0 + s1) + (s2 + s3);
    }
  }
#pragma unroll
  for (int d = 0; d < 64; ++d) sv[d] = fmaxf(0.0f, sv[d]);
  float* outg = l1p + (size_t)g * 128;
#pragma unroll 2
  for (int e = 0; e < 128; ++e) {
    const float* wr = w2 + (e << 6);
    float s0 = 0.f, s1 = 0.f, s2 = 0.f, s3 = 0.f;
#pragma unroll
    for (int c = 0; c < 64; c += 4) {
      s0 = fmaf(wr[c], sv[c], s0);
      s1 = fmaf(wr[c + 1], sv[c + 1], s1);
      s2 = fmaf(wr[c + 2], sv[c + 2], s2);
      s3 = fmaf(wr[c + 3], sv[c + 3], s3);
    }
    float v = fmaxf(0.0f, b2[e] + ((s0 + s1) + (s2 + s3)));
    v = red32_maxf(v);
    if ((lane & 31) == 31) outg[e] = v;
  }
}

// ---------------------------------------------------------------------------
// SA2 layer kernels: lane = point (m), A row in registers (float4 packed
// [d/4][m][4] intermediates), weights via wave-uniform scalar path.
// ---------------------------------------------------------------------------
__global__ __launch_bounds__(256, 2) void k_sa2_l0(
    const float* __restrict__ new_xyz, const float* __restrict__ l1p,
    const float* __restrict__ w0, const float* __restrict__ b0,
    float4* __restrict__ h0t4) {
  const int pb = blockIdx.x >> 2, ds = blockIdx.x & 3;
  const int t = threadIdx.x;
  const int d0 = ds * 32;
  const int m = pb * 256 + t;
  const float ax = new_xyz[(size_t)m * 3], ay = new_xyz[(size_t)m * 3 + 1],
              az = new_xyz[(size_t)m * 3 + 2];
  float4 av[32];
  const float4* lp = (const float4*)(l1p + (size_t)m * 128);
#pragma unroll
  for (int i = 0; i < 32; ++i) av[i] = lp[i];
  for (int dq = 0; dq < 8; ++dq) {
    float o[4];
#pragma unroll
    for (int k = 0; k < 4; ++k) {
      const int dd = 4 * dq + k;
      const float* wr = w0 + (size_t)(d0 + dd) * 131;
      float s = fmaf(wr[0], ax, fmaf(wr[1], ay, fmaf(wr[2], az, b0[d0 + dd])));
      float s0 = 0.f, s1 = 0.f, s2 = 0.f, s3 = 0.f;
#pragma unroll
      for (int i = 0; i < 32; ++i) {
        s0 = fmaf(wr[3 + 4 * i], av[i].x, s0);
        s1 = fmaf(wr[4 + 4 * i], av[i].y, s1);
        s2 = fmaf(wr[5 + 4 * i], av[i].z, s2);
        s3 = fmaf(wr[6 + 4 * i], av[i].w, s3);
      }
      o[k] = fmaxf(0.0f, s + ((s0 + s1) + (s2 + s3)));
    }
    h0t4[(size_t)(ds * 8 + dq) * 16384 + m] =
        make_float4(o[0], o[1], o[2], o[3]);
  }
}

__global__ __launch_bounds__(256, 2) void k_sa2_l1(
    const float4* __restrict__ h0t4, const float* __restrict__ w1,
    const float* __restrict__ b1, float4* __restrict__ h1t4) {
  const int pb = blockIdx.x >> 2, ds = blockIdx.x & 3;
  const int t = threadIdx.x;
  const int d0 = ds * 32;
  const int m = pb * 256 + t;
  float4 a4[32];
#pragma unroll
  for (int i = 0; i < 32; ++i) a4[i] = h0t4[(size_t)i * 16384 + m];
  for (int dq = 0; dq < 8; ++dq) {
    float o[4];
#pragma unroll
    for (int k = 0; k < 4; ++k) {
      const int dd = 4 * dq + k;
      const float* wr = w1 + (size_t)(d0 + dd) * 128;
      float s0 = 0.f, s1 = 0.f, s2 = 0.f, s3 = 0.f;
#pragma unroll
      for (int i = 0; i < 32; ++i) {
        s0 = fmaf(wr[4 * i], a4[i].x, s0);
        s1 = fmaf(wr[4 * i + 1], a4[i].y, s1);
        s2 = fmaf(wr[4 * i + 2], a4[i].z, s2);
        s3 = fmaf(wr[4 * i + 3], a4[i].w, s3);
      }
      o[k] = fmaxf(0.0f, b1[d0 + dd] + ((s0 + s1) + (s2 + s3)));
    }
    h1t4[(size_t)(ds * 8 + dq) * 16384 + m] =
        make_float4(o[0], o[1], o[2], o[3]);
  }
}

__global__ __launch_bounds__(256, 2) void k_sa2_l2max(
    const float4* __restrict__ h1t4, const float* __restrict__ w2,
    const float* __restrict__ b2, float* __restrict__ pmax) {
  const int pb = blockIdx.x >> 3, ds = blockIdx.x & 7;
  const int t = threadIdx.x;
  const int d0 = ds * 32;
  const int m = pb * 256 + t;
  const int b = m >> 9;
  const int wc = ((pb << 2) + (t >> 6)) & 7;  // wave-chunk within batch (0..7)
  float4 a4[32];
#pragma unroll
  for (int i = 0; i < 32; ++i) a4[i] = h1t4[(size_t)i * 16384 + m];
  for (int dq = 0; dq < 8; ++dq) {
#pragma unroll
    for (int k = 0; k < 4; ++k) {
      const int dd = 4 * dq + k;
      const float* wr = w2 + (size_t)(d0 + dd) * 128;
      float s0 = 0.f, s1 = 0.f, s2 = 0.f, s3 = 0.f;
#pragma unroll
      for (int i = 0; i < 32; ++i) {
        s0 = fmaf(wr[4 * i], a4[i].x, s0);
        s1 = fmaf(wr[4 * i + 1], a4[i].y, s1);
        s2 = fmaf(wr[4 * i + 2], a4[i].z, s2);
        s3 = fmaf(wr[4 * i + 3], a4[i].w, s3);
      }
      float v = fmaxf(0.0f, b2[d0 + dd] + ((s0 + s1) + (s2 + s3)));
      v = red64_maxf(v);  // wave max, valid at lane 63
      if ((t & 63) == 63) pmax[((size_t)(b << 3) + wc) * 256 + d0 + dd] = v;
    }
  }
}

// ---------------------------------------------------------------------------
// K7: head. One block (1 wave) per batch. obj = max over 8 wave-partials,
// pose MLP + fusion MLP + two scalar heads.
// ---------------------------------------------------------------------------
__global__ __launch_bounds__(64) void k_head(
    const float* __restrict__ pmax, const float* __restrict__ grasp,
    const float* __restrict__ initp, const float* __restrict__ finalp,
    const int* __restrict__ surf, const float* __restrict__ embi,
    const float* __restrict__ embf, const float* __restrict__ pw0,
    const float* __restrict__ pb0, const float* __restrict__ pw1,
    const float* __restrict__ pb1, const float* __restrict__ pw2,
    const float* __restrict__ pb2, const float* __restrict__ fw0,
    const float* __restrict__ fb0, const float* __restrict__ fw1,
    const float* __restrict__ fb1, const float* __restrict__ osw,
    const float* __restrict__ osb, const float* __restrict__ ocw,
    const float* __restrict__ ocb, float* __restrict__ out) {
  __shared__ float obj[256], xb[37], A0[64], A1[128], A2[128], F0[128], HID[64];
  const int b = blockIdx.x, l = threadIdx.x;
  const float* pm = pmax + (size_t)b * 2048;
  for (int e = l; e < 256; e += 64) {
    float v = pm[e];
#pragma unroll
    for (int w = 1; w < 8; ++w) v = fmaxf(v, pm[w * 256 + e]);
    obj[e] = v;
  }
  if (l < 7) xb[l] = grasp[b * 7 + l];
  else if (l < 14) xb[l] = initp[b * 7 + l - 7];
  else if (l < 21) xb[l] = finalp[b * 7 + l - 14];
  else if (l < 29) xb[l] = embi[surf[b * 2] * 8 + l - 21];
  else if (l < 37) xb[l] = embf[surf[b * 2 + 1] * 8 + l - 29];
  __syncthreads();
  {
    float s = pb0[l];
    const float* wr = pw0 + l * 37;
#pragma unroll
    for (int c = 0; c < 37; ++c) s = fmaf(xb[c], wr[c], s);
    A0[l] = fmaxf(0.f, s);
  }
  __syncthreads();
#pragma unroll
  for (int dd = 0; dd < 2; ++dd) {
    const int d = l + dd * 64;
    float s = pb1[d];
    const float* wr = pw1 + d * 64;
#pragma unroll
    for (int c = 0; c < 64; ++c) s = fmaf(A0[c], wr[c], s);
    A1[d] = fmaxf(0.f, s);
  }
  __syncthreads();
#pragma unroll
  for (int dd = 0; dd < 2; ++dd) {
    const int d = l + dd * 64;
    float s = pb2[d];
    const float* wr = pw2 + d * 128;
#pragma unroll 16
    for (int c = 0; c < 128; ++c) s = fmaf(A1[c], wr[c], s);
    A2[d] = fmaxf(0.f, s);
  }
  __syncthreads();
#pragma unroll
  for (int dd = 0; dd < 2; ++dd) {
    const int d = l + dd * 64;
    float s = fb0[d];
    const float* wr = fw0 + d * 384;
#pragma unroll 16
    for (int c = 0; c < 256; ++c) s = fmaf(obj[c], wr[c], s);
#pragma unroll 16
    for (int c = 0; c < 128; ++c) s = fmaf(A2[c], wr[256 + c], s);
    F0[d] = fmaxf(0.f, s);
  }
  __syncthreads();
  {
    float s = fb1[l];
    const float* wr = fw1 + l * 128;
#pragma unroll 16
    for (int c = 0; c < 128; ++c) s = fmaf(F0[c], wr[c], s);
    HID[l] = fmaxf(0.f, s);
  }
  __syncthreads();
  float v1 = HID[l] * osw[l];
  float v2 = HID[l] * ocw[l];
#pragma unroll
  for (int off = 1; off < 64; off <<= 1) {
    v1 += __shfl_xor(v1, off);
    v2 += __shfl_xor(v2, off);
  }
  if (l == 0) {
    out[b] = v1 + osb[0];
    out[32 + b] = v2 + ocb[0];
  }
}

extern "C" void kernel_launch(void* const* d_in, const int* in_sizes, int n_in,
                              void* d_out, int out_size, void* d_ws, size_t ws_size,
                              hipStream_t stream) {
  const float* points  = (const float*)d_in[0];
  const float* grasp   = (const float*)d_in[1];
  const float* initp   = (const float*)d_in[2];
  const float* finalp  = (const float*)d_in[3];
  const int*   surf    = (const int*)d_in[4];
  const float* sa1_w0  = (const float*)d_in[5];
  const float* sa1_b0  = (const float*)d_in[6];
  const float* sa1_w1  = (const float*)d_in[7];
  const float* sa1_b1  = (const float*)d_in[8];
  const float* sa1_w2  = (const float*)d_in[9];
  const float* sa1_b2  = (const float*)d_in[10];
  const float* sa2_w0  = (const float*)d_in[11];
  const float* sa2_b0  = (const float*)d_in[12];
  const float* sa2_w1  = (const float*)d_in[13];
  const float* sa2_b1  = (const float*)d_in[14];
  const float* sa2_w2  = (const float*)d_in[15];
  const float* sa2_b2  = (const float*)d_in[16];
  const float* embi    = (const float*)d_in[17];
  const float* embf    = (const float*)d_in[18];
  const float* pe_w0   = (const float*)d_in[19];
  const float* pe_b0   = (const float*)d_in[20];
  const float* pe_w1   = (const float*)d_in[21];
  const float* pe_b1   = (const float*)d_in[22];
  const float* pe_w2   = (const float*)d_in[23];
  const float* pe_b2   = (const float*)d_in[24];
  const float* fu_w0   = (const float*)d_in[25];
  const float* fu_b0   = (const float*)d_in[26];
  const float* fu_w1   = (const float*)d_in[27];
  const float* fu_b1   = (const float*)d_in[28];
  const float* os_w    = (const float*)d_in[29];
  const float* os_b    = (const float*)d_in[30];
  const float* oc_w    = (const float*)d_in[31];
  const float* oc_b    = (const float*)d_in[32];

  char* ws = (char*)d_ws;
  // layout (bytes):
  int*    fidx    = (int*)(ws + 0);               //  65536
  float*  new_xyz = (float*)(ws + 65536);         // 196608
  int*    gidx    = (int*)(ws + 262144);          // 2097152
  float*  l1p     = (float*)(ws + 2359296);       // 8388608 (reused as h1t)
  float4* h0t4    = (float4*)(ws + 10747904);     // 8388608
  float*  pmax    = (float*)(ws + 19136512);      // 262144  -> end 19398656
  float4* h1t4    = (float4*)l1p;  // l1_points dead after k_sa2_l0
  const size_t base_end = 19398656;

  float* out = (float*)d_out;

  k_fps<<<32, 256, 0, stream>>>(points, fidx);
  k_ballq<<<4096, 256, 0, stream>>>(points, fidx, new_xyz, gidx);

  // SA1: split path with svT staged in ws (tiered by ws_size), else fused.
  const size_t NSAMP = 524288;  // 32*512*32
  int SC = 0;
  if (ws_size >= base_end + NSAMP * 256) SC = (int)NSAMP;       // +134.2 MB
  else if (ws_size >= base_end + (NSAMP / 4) * 256) SC = 131072;  // +33.5 MB
  if (SC > 0) {
    float4* svT = (float4*)(ws + base_end);
    const int nc = (int)(NSAMP / SC);
    for (int ci = 0; ci < nc; ++ci) {
      k_sa1a<<<SC / 256, 256, 0, stream>>>(points, new_xyz, gidx, sa1_w0,
                                           sa1_b0, sa1_w1, sa1_b1, svT,
                                           ci * SC, SC);
      k_sa1b<<<SC / 256, 256, 0, stream>>>(svT, sa1_w2, sa1_b2, l1p, ci * SC,
                                           SC);
    }
  } else {
    k_sa1_fused<<<2048, 256, 0, stream>>>(points, new_xyz, gidx, sa1_w0,
                                          sa1_b0, sa1_w1, sa1_b1, sa1_w2,
                                          sa1_b2, l1p);
  }

  k_sa2_l0<<<256, 256, 0, stream>>>(new_xyz, l1p, sa2_w0, sa2_b0, h0t4);
  k_sa2_l1<<<256, 256, 0, stream>>>(h0t4, sa2_w1, sa2_b1, h1t4);
  k_sa2_l2max<<<512, 256, 0, stream>>>(h1t4, sa2_w2, sa2_b2, pmax);
  k_head<<<32, 64, 0, stream>>>(pmax, grasp, initp, finalp, surf, embi, embf,
                                pe_w0, pe_b0, pe_w1, pe_b1, pe_w2, pe_b2, fu_w0,
                                fu_b0, fu_w1, fu_b1, os_w, os_b, oc_w, oc_b, out);
}

// Round 6
// 665.656 us; speedup vs baseline: 1.7957x; 1.0806x over previous
//
#include <hip/hip_runtime.h>

#define DEVINL __device__ __forceinline__

// Exact (no-FMA-contraction) squared distance in the same rounding order as
// numpy/jax fp32: ((dx*dx + dy*dy) + dz*dz). Discrete decisions (FPS argmax,
// ball-query radius compare) depend on bit-exactness.
DEVINL float sq3(float ax, float ay, float az, float bx, float by, float bz) {
  float dx = __fsub_rn(ax, bx), dy = __fsub_rn(ay, by), dz = __fsub_rn(az, bz);
  return __fadd_rn(__fadd_rn(__fmul_rn(dx, dx), __fmul_rn(dy, dy)), __fmul_rn(dz, dz));
}

// DPP max-trees (VALU pipe). old=own so invalid-lane results are identity-safe
// for max. Sequence row_shr:1/2/4/8 + row_bcast:15 + row_bcast:31 -> 64-lane
// reduce, result valid at lane 63 (proven in rounds 4-5, absmax 0.0).
template <int CTRL>
DEVINL float dpp_maxf(float v) {
  int o = __builtin_amdgcn_update_dpp(__float_as_int(v), __float_as_int(v),
                                      CTRL, 0xf, 0xf, false);
  return fmaxf(v, __int_as_float(o));
}
DEVINL float red32_maxf(float v) {  // 32-lane group max -> valid at lanes 31,63
  v = dpp_maxf<0x111>(v); v = dpp_maxf<0x112>(v); v = dpp_maxf<0x114>(v);
  v = dpp_maxf<0x118>(v); v = dpp_maxf<0x142>(v);
  return v;
}
DEVINL float red64_maxf(float v) {  // 64-lane max -> valid at lane 63
  v = red32_maxf(v); v = dpp_maxf<0x143>(v);
  return v;
}
// u64 packed-key max tree: both halves move with the same DPP ctrl (pair stays
// consistent: both read the same source lane). Valid at lane 63 after 6 levels.
template <int CTRL>
DEVINL unsigned long long dpp_maxk(unsigned long long k) {
  const unsigned lo = (unsigned)k, hi = (unsigned)(k >> 32);
  const unsigned olo = (unsigned)__builtin_amdgcn_update_dpp(
      (int)lo, (int)lo, CTRL, 0xf, 0xf, false);
  const unsigned ohi = (unsigned)__builtin_amdgcn_update_dpp(
      (int)hi, (int)hi, CTRL, 0xf, 0xf, false);
  const unsigned long long ok = ((unsigned long long)ohi << 32) | olo;
  return (ok > k) ? ok : k;
}
DEVINL unsigned long long red64_maxk(unsigned long long k) {
  k = dpp_maxk<0x111>(k); k = dpp_maxk<0x112>(k); k = dpp_maxk<0x114>(k);
  k = dpp_maxk<0x118>(k); k = dpp_maxk<0x142>(k); k = dpp_maxk<0x143>(k);
  return k;
}

// ---------------------------------------------------------------------------
// K1: farthest point sampling. One block per batch (32), 256 threads, points
// cached in registers (8/thread). Round-6 structure: per step the j-loop
// tracks (bv,bi); one packed-u64 DPP tree (val<<32 | 2047-idx: u64 max ==
// first-occurrence argmax); lane 63 of each wave reads its CANDIDATE's coords
// pre-barrier (parallel across waves) and publishes (key, coords); after one
// barrier every thread combines 4 (key,coords) pairs -> next centroid is in
// registers, removing the chained post-barrier centroid LDS read.
// ---------------------------------------------------------------------------
__global__ __launch_bounds__(256) void k_fps(const float* __restrict__ xyz,
                                             int* __restrict__ fidx) {
  const int b = blockIdx.x, t = threadIdx.x;
  __shared__ float xs[2048], ys[2048], zs[2048];
  __shared__ unsigned long long skey[2][4];
  __shared__ float4 scoord[2][4];
  const float* P = xyz + (size_t)b * 6144;
  for (int i = t; i < 2048; i += 256) {
    xs[i] = P[3 * i]; ys[i] = P[3 * i + 1]; zs[i] = P[3 * i + 2];
  }
  __syncthreads();
  float px[8], py[8], pz[8], dist[8];
#pragma unroll
  for (int j = 0; j < 8; ++j) {
    const int idx = j * 256 + t;
    px[j] = xs[idx]; py[j] = ys[idx]; pz[j] = zs[idx];
    dist[j] = 1e10f;
  }
  int far = 0;
  float cx = xs[0], cy = ys[0], cz = zs[0];
  int* out = fidx + b * 512;
  for (int it = 0; it < 512; ++it) {
    if (t == 0) out[it] = far;  // emit BEFORE update (scan emits carry's far)
    float bv = -1.0f;
    int bi = 0;
#pragma unroll
    for (int j = 0; j < 8; ++j) {
      const float d = sq3(px[j], py[j], pz[j], cx, cy, cz);
      const float nd = fminf(dist[j], d);
      dist[j] = nd;
      if (nd > bv) { bv = nd; bi = j * 256 + t; }  // strict >: smallest idx kept
    }
    // packed key: larger value wins; tie -> larger (2047-idx) -> smaller idx
    unsigned long long key =
        ((unsigned long long)__float_as_uint(bv) << 32) | (unsigned)(2047 - bi);
    key = red64_maxk(key);  // wave winner at lane 63
    const int par = it & 1;
    if ((t & 63) == 63) {
      const int widx = 2047 - (int)((unsigned)key & 2047u);
      skey[par][t >> 6] = key;
      scoord[par][t >> 6] = make_float4(xs[widx], ys[widx], zs[widx], 0.0f);
    }
    __syncthreads();
    unsigned long long k0 = skey[par][0], k1 = skey[par][1];
    unsigned long long k2 = skey[par][2], k3 = skey[par][3];
    float4 c0 = scoord[par][0], c1 = scoord[par][1];
    float4 c2 = scoord[par][2], c3 = scoord[par][3];
    if (k1 > k0) { k0 = k1; c0 = c1; }
    if (k3 > k2) { k2 = k3; c2 = c3; }
    if (k2 > k0) { k0 = k2; c0 = c2; }
    far = 2047 - (int)((unsigned)k0 & 2047u);
    cx = c0.x; cy = c0.y; cz = c0.z;
  }
}

// ---------------------------------------------------------------------------
// K2: ball query. One wave per centroid (16384 waves). Collect first 32
// ascending indices with d2 <= r^2; pad with first hit. Also writes new_xyz.
// ---------------------------------------------------------------------------
__global__ __launch_bounds__(256) void k_ballq(const float* __restrict__ xyz,
                                               const int* __restrict__ fidx,
                                               float* __restrict__ new_xyz,
                                               int* __restrict__ gidx) {
  const int gw = (blockIdx.x * 256 + threadIdx.x) >> 6;  // centroid id
  const int lane = threadIdx.x & 63;
  const int b = gw >> 9;
  const float* P = xyz + (size_t)b * 6144;
  const int cidx = fidx[gw];
  const float cx = P[3 * cidx], cy = P[3 * cidx + 1], cz = P[3 * cidx + 2];
  if (lane < 3) new_xyz[(size_t)gw * 3 + lane] = P[3 * cidx + lane];
  int* g = gidx + (size_t)gw * 32;
  int base = 0, firstidx = -1;
  for (int c0 = 0; c0 < 2048; c0 += 64) {
    const int idx = c0 + lane;
    const float d = sq3(cx, cy, cz, P[3 * idx], P[3 * idx + 1], P[3 * idx + 2]);
    const bool in = !(d > 0.04f);  // matches: exclude where sqr > r*r
    const unsigned long long m = __ballot(in);
    if (firstidx < 0 && m) firstidx = c0 + (int)__builtin_ctzll(m);
    if (in) {
      const int pos = base + (int)__popcll(m & ((1ull << lane) - 1ull));
      if (pos < 32) g[pos] = idx;
    }
    base += (int)__popcll(m);
    if (base >= 32) break;  // wave-uniform
  }
  for (int pos = base + lane; pos < 32; pos += 64) g[pos] = firstidx;
}

// ---------------------------------------------------------------------------
// SA1 split: kA = layers 0+1 -> svT staged in workspace (transposed float4
// [d1/4][sample]); kB = layer 2 + 32-lane group max. Both ~75-85 reg
// watermark. Weights on the wave-uniform scalar path.
// ---------------------------------------------------------------------------
__global__ __launch_bounds__(256, 4) void k_sa1a(
    const float* __restrict__ xyz, const float* __restrict__ new_xyz,
    const int* __restrict__ gidx, const float* __restrict__ w0,
    const float* __restrict__ b0, const float* __restrict__ w1,
    const float* __restrict__ b1, float4* __restrict__ svT, int p0, int SC) {
  const int q = blockIdx.x * 256 + threadIdx.x;  // chunk-local sample
  const int p = p0 + q;                          // global sample id
  const int g = p >> 5;
  const int b = p >> 14;
  const int src = gidx[p];
  const float* P = xyz + (size_t)b * 6144;
  const float nx = new_xyz[(size_t)g * 3], ny = new_xyz[(size_t)g * 3 + 1],
              nz = new_xyz[(size_t)g * 3 + 2];
  const float x = P[3 * src] - nx, y = P[3 * src + 1] - ny,
              z = P[3 * src + 2] - nz;
  float h0[64];
#pragma unroll
  for (int d = 0; d < 64; ++d) {
    h0[d] = fmaxf(0.0f, fmaf(w0[3 * d], x,
                             fmaf(w0[3 * d + 1], y,
                                  fmaf(w0[3 * d + 2], z, b0[d]))));
  }
  for (int d4 = 0; d4 < 16; ++d4) {
    float o[4];
#pragma unroll
    for (int k = 0; k < 4; ++k) {
      const int d1 = 4 * d4 + k;
      const float* wr = w1 + (d1 << 6);
      float s0 = 0.f, s1 = 0.f, s2 = 0.f, s3 = 0.f;
#pragma unroll
      for (int c = 0; c < 64; c += 4) {
        s0 = fmaf(wr[c], h0[c], s0);
        s1 = fmaf(wr[c + 1], h0[c + 1], s1);
        s2 = fmaf(wr[c + 2], h0[c + 2], s2);
        s3 = fmaf(wr[c + 3], h0[c + 3], s3);
      }
      o[k] = fmaxf(0.0f, b1[d1] + ((s0 + s1) + (s2 + s3)));
    }
    svT[(size_t)d4 * SC + q] = make_float4(o[0], o[1], o[2], o[3]);
  }
}

__global__ __launch_bounds__(256, 4) void k_sa1b(
    const float4* __restrict__ svT, const float* __restrict__ w2,
    const float* __restrict__ b2, float* __restrict__ l1p, int p0, int SC) {
  const int q = blockIdx.x * 256 + threadIdx.x;
  const int p = p0 + q;
  const int g = p >> 5;
  const int lane = threadIdx.x & 63;
  float sv[64];
#pragma unroll
  for (int i = 0; i < 16; ++i) {
    const float4 f = svT[(size_t)i * SC + q];
    sv[4 * i] = f.x; sv[4 * i + 1] = f.y; sv[4 * i + 2] = f.z;
    sv[4 * i + 3] = f.w;
  }
  float* outg = l1p + (size_t)g * 128;
  for (int e = 0; e < 128; ++e) {
    const float* wr = w2 + (e << 6);
    float s0 = 0.f, s1 = 0.f, s2 = 0.f, s3 = 0.f;
#pragma unroll
    for (int c = 0; c < 64; c += 4) {
      s0 = fmaf(wr[c], sv[c], s0);
      s1 = fmaf(wr[c + 1], sv[c + 1], s1);
      s2 = fmaf(wr[c + 2], sv[c + 2], s2);
      s3 = fmaf(wr[c + 3], sv[c + 3], s3);
    }
    float v = fmaxf(0.0f, b2[e] + ((s0 + s1) + (s2 + s3)));
    v = red32_maxf(v);  // group max, valid at lanes 31 & 63
    if ((lane & 31) == 31) outg[e] = v;
  }
}

// Fused fallback if ws_size can't hold svT.
__global__ __launch_bounds__(256, 2) void k_sa1_fused(
    const float* __restrict__ xyz, const float* __restrict__ new_xyz,
    const int* __restrict__ gidx, const float* __restrict__ w0,
    const float* __restrict__ b0, const float* __restrict__ w1,
    const float* __restrict__ b1, const float* __restrict__ w2,
    const float* __restrict__ b2, float* __restrict__ l1p) {
  const int t = threadIdx.x;
  const int p = blockIdx.x * 256 + t;
  const int g = p >> 5;
  const int b = p >> 14;
  const int lane = t & 63;
  const int src = gidx[p];
  const float* P = xyz + (size_t)b * 6144;
  const float nx = new_xyz[(size_t)g * 3], ny = new_xyz[(size_t)g * 3 + 1],
              nz = new_xyz[(size_t)g * 3 + 2];
  const float x = P[3 * src] - nx, y = P[3 * src + 1] - ny,
              z = P[3 * src + 2] - nz;
  float sv[64];
#pragma unroll
  for (int d = 0; d < 64; ++d) sv[d] = b1[d];
#pragma unroll
  for (int half = 0; half < 2; ++half) {
    float h0[32];
#pragma unroll
    for (int d = 0; d < 32; ++d) {
      const int dd = half * 32 + d;
      h0[d] = fmaxf(0.0f, fmaf(w0[3 * dd], x,
                               fmaf(w0[3 * dd + 1], y,
                                    fmaf(w0[3 * dd + 2], z, b0[dd]))));
    }
#pragma unroll
    for (int d1 = 0; d1 < 64; ++d1) {
      const float* wr = w1 + (d1 << 6) + half * 32;
      float s0 = 0.f, s1 = 0.f, s2 = 0.f, s3 = 0.f;
#pragma unroll
      for (int c = 0; c < 32; c += 4) {
        s0 = fmaf(wr[c], h0[c], s0);
        s1 = fmaf(wr[c + 1], h0[c + 1], s1);
        s2 = fmaf(wr[c + 2], h0[c + 2], s2);
        s3 = fmaf(wr[c + 3], h0[c + 3], s3);
      }
      sv[d1] += (s0 + s1) + (s2 + s3);
    }
  }
#pragma unroll
  for (int d = 0; d < 64; ++d) sv[d] = fmaxf(0.0f, sv[d]);
  float* outg = l1p + (size_t)g * 128;
#pragma unroll 2
  for (int e = 0; e < 128; ++e) {
    const float* wr = w2 + (e << 6);
    float s0 = 0.f, s1 = 0.f, s2 = 0.f, s3 = 0.f;
#pragma unroll
    for (int c = 0; c < 64; c += 4) {
      s0 = fmaf(wr[c], sv[c], s0);
      s1 = fmaf(wr[c + 1], sv[c + 1], s1);
      s2 = fmaf(wr[c + 2], sv[c + 2], s2);
      s3 = fmaf(wr[c + 3], sv[c + 3], s3);
    }
    float v = fmaxf(0.0f, b2[e] + ((s0 + s1) + (s2 + s3)));
    v = red32_maxf(v);
    if ((lane & 31) == 31) outg[e] = v;
  }
}

// ---------------------------------------------------------------------------
// SA2 layer kernels: lane = point (m), A row in registers (float4 packed
// [d/4][m][4] intermediates), weights via wave-uniform scalar path.
// Round 6: finer ds-chunks (16 dims) -> 2x grid -> 2-4 blocks/CU for latency
// hiding (these were 1 block/CU latency-bound).
// ---------------------------------------------------------------------------
__global__ __launch_bounds__(256, 2) void k_sa2_l0(
    const float* __restrict__ new_xyz, const float* __restrict__ l1p,
    const float* __restrict__ w0, const float* __restrict__ b0,
    float4* __restrict__ h0t4) {
  const int pb = blockIdx.x >> 3, ds = blockIdx.x & 7;  // 8 chunks x 16 dims
  const int t = threadIdx.x;
  const int d0 = ds * 16;
  const int m = pb * 256 + t;
  const float ax = new_xyz[(size_t)m * 3], ay = new_xyz[(size_t)m * 3 + 1],
              az = new_xyz[(size_t)m * 3 + 2];
  float4 av[32];
  const float4* lp = (const float4*)(l1p + (size_t)m * 128);
#pragma unroll
  for (int i = 0; i < 32; ++i) av[i] = lp[i];
  for (int dq = 0; dq < 4; ++dq) {
    float o[4];
#pragma unroll
    for (int k = 0; k < 4; ++k) {
      const int dd = 4 * dq + k;
      const float* wr = w0 + (size_t)(d0 + dd) * 131;
      float s = fmaf(wr[0], ax, fmaf(wr[1], ay, fmaf(wr[2], az, b0[d0 + dd])));
      float s0 = 0.f, s1 = 0.f, s2 = 0.f, s3 = 0.f;
#pragma unroll
      for (int i = 0; i < 32; ++i) {
        s0 = fmaf(wr[3 + 4 * i], av[i].x, s0);
        s1 = fmaf(wr[4 + 4 * i], av[i].y, s1);
        s2 = fmaf(wr[5 + 4 * i], av[i].z, s2);
        s3 = fmaf(wr[6 + 4 * i], av[i].w, s3);
      }
      o[k] = fmaxf(0.0f, s + ((s0 + s1) + (s2 + s3)));
    }
    h0t4[(size_t)(ds * 4 + dq) * 16384 + m] =
        make_float4(o[0], o[1], o[2], o[3]);
  }
}

__global__ __launch_bounds__(256, 2) void k_sa2_l1(
    const float4* __restrict__ h0t4, const float* __restrict__ w1,
    const float* __restrict__ b1, float4* __restrict__ h1t4) {
  const int pb = blockIdx.x >> 3, ds = blockIdx.x & 7;  // 8 chunks x 16 dims
  const int t = threadIdx.x;
  const int d0 = ds * 16;
  const int m = pb * 256 + t;
  float4 a4[32];
#pragma unroll
  for (int i = 0; i < 32; ++i) a4[i] = h0t4[(size_t)i * 16384 + m];
  for (int dq = 0; dq < 4; ++dq) {
    float o[4];
#pragma unroll
    for (int k = 0; k < 4; ++k) {
      const int dd = 4 * dq + k;
      const float* wr = w1 + (size_t)(d0 + dd) * 128;
      float s0 = 0.f, s1 = 0.f, s2 = 0.f, s3 = 0.f;
#pragma unroll
      for (int i = 0; i < 32; ++i) {
        s0 = fmaf(wr[4 * i], a4[i].x, s0);
        s1 = fmaf(wr[4 * i + 1], a4[i].y, s1);
        s2 = fmaf(wr[4 * i + 2], a4[i].z, s2);
        s3 = fmaf(wr[4 * i + 3], a4[i].w, s3);
      }
      o[k] = fmaxf(0.0f, b1[d0 + dd] + ((s0 + s1) + (s2 + s3)));
    }
    h1t4[(size_t)(ds * 4 + dq) * 16384 + m] =
        make_float4(o[0], o[1], o[2], o[3]);
  }
}

__global__ __launch_bounds__(256, 2) void k_sa2_l2max(
    const float4* __restrict__ h1t4, const float* __restrict__ w2,
    const float* __restrict__ b2, float* __restrict__ pmax) {
  const int pb = blockIdx.x >> 4, ds = blockIdx.x & 15;  // 16 chunks x 16 dims
  const int t = threadIdx.x;
  const int d0 = ds * 16;
  const int m = pb * 256 + t;
  const int b = m >> 9;
  const int wc = ((pb << 2) + (t >> 6)) & 7;  // wave-chunk within batch (0..7)
  float4 a4[32];
#pragma unroll
  for (int i = 0; i < 32; ++i) a4[i] = h1t4[(size_t)i * 16384 + m];
  for (int dq = 0; dq < 4; ++dq) {
#pragma unroll
    for (int k = 0; k < 4; ++k) {
      const int dd = 4 * dq + k;
      const float* wr = w2 + (size_t)(d0 + dd) * 128;
      float s0 = 0.f, s1 = 0.f, s2 = 0.f, s3 = 0.f;
#pragma unroll
      for (int i = 0; i < 32; ++i) {
        s0 = fmaf(wr[4 * i], a4[i].x, s0);
        s1 = fmaf(wr[4 * i + 1], a4[i].y, s1);
        s2 = fmaf(wr[4 * i + 2], a4[i].z, s2);
        s3 = fmaf(wr[4 * i + 3], a4[i].w, s3);
      }
      float v = fmaxf(0.0f, b2[d0 + dd] + ((s0 + s1) + (s2 + s3)));
      v = red64_maxf(v);  // wave max, valid at lane 63
      if ((t & 63) == 63) pmax[((size_t)(b << 3) + wc) * 256 + d0 + dd] = v;
    }
  }
}

// ---------------------------------------------------------------------------
// K7: head. One block (1 wave) per batch. obj = max over 8 wave-partials,
// pose MLP + fusion MLP + two scalar heads.
// ---------------------------------------------------------------------------
__global__ __launch_bounds__(64) void k_head(
    const float* __restrict__ pmax, const float* __restrict__ grasp,
    const float* __restrict__ initp, const float* __restrict__ finalp,
    const int* __restrict__ surf, const float* __restrict__ embi,
    const float* __restrict__ embf, const float* __restrict__ pw0,
    const float* __restrict__ pb0, const float* __restrict__ pw1,
    const float* __restrict__ pb1, const float* __restrict__ pw2,
    const float* __restrict__ pb2, const float* __restrict__ fw0,
    const float* __restrict__ fb0, const float* __restrict__ fw1,
    const float* __restrict__ fb1, const float* __restrict__ osw,
    const float* __restrict__ osb, const float* __restrict__ ocw,
    const float* __restrict__ ocb, float* __restrict__ out) {
  __shared__ float obj[256], xb[37], A0[64], A1[128], A2[128], F0[128], HID[64];
  const int b = blockIdx.x, l = threadIdx.x;
  const float* pm = pmax + (size_t)b * 2048;
  for (int e = l; e < 256; e += 64) {
    float v = pm[e];
#pragma unroll
    for (int w = 1; w < 8; ++w) v = fmaxf(v, pm[w * 256 + e]);
    obj[e] = v;
  }
  if (l < 7) xb[l] = grasp[b * 7 + l];
  else if (l < 14) xb[l] = initp[b * 7 + l - 7];
  else if (l < 21) xb[l] = finalp[b * 7 + l - 14];
  else if (l < 29) xb[l] = embi[surf[b * 2] * 8 + l - 21];
  else if (l < 37) xb[l] = embf[surf[b * 2 + 1] * 8 + l - 29];
  __syncthreads();
  {
    float s = pb0[l];
    const float* wr = pw0 + l * 37;
#pragma unroll
    for (int c = 0; c < 37; ++c) s = fmaf(xb[c], wr[c], s);
    A0[l] = fmaxf(0.f, s);
  }
  __syncthreads();
#pragma unroll
  for (int dd = 0; dd < 2; ++dd) {
    const int d = l + dd * 64;
    float s = pb1[d];
    const float* wr = pw1 + d * 64;
#pragma unroll
    for (int c = 0; c < 64; ++c) s = fmaf(A0[c], wr[c], s);
    A1[d] = fmaxf(0.f, s);
  }
  __syncthreads();
#pragma unroll
  for (int dd = 0; dd < 2; ++dd) {
    const int d = l + dd * 64;
    float s = pb2[d];
    const float* wr = pw2 + d * 128;
#pragma unroll 16
    for (int c = 0; c < 128; ++c) s = fmaf(A1[c], wr[c], s);
    A2[d] = fmaxf(0.f, s);
  }
  __syncthreads();
#pragma unroll
  for (int dd = 0; dd < 2; ++dd) {
    const int d = l + dd * 64;
    float s = fb0[d];
    const float* wr = fw0 + d * 384;
#pragma unroll 16
    for (int c = 0; c < 256; ++c) s = fmaf(obj[c], wr[c], s);
#pragma unroll 16
    for (int c = 0; c < 128; ++c) s = fmaf(A2[c], wr[256 + c], s);
    F0[d] = fmaxf(0.f, s);
  }
  __syncthreads();
  {
    float s = fb1[l];
    const float* wr = fw1 + l * 128;
#pragma unroll 16
    for (int c = 0; c < 128; ++c) s = fmaf(F0[c], wr[c], s);
    HID[l] = fmaxf(0.f, s);
  }
  __syncthreads();
  float v1 = HID[l] * osw[l];
  float v2 = HID[l] * ocw[l];
#pragma unroll
  for (int off = 1; off < 64; off <<= 1) {
    v1 += __shfl_xor(v1, off);
    v2 += __shfl_xor(v2, off);
  }
  if (l == 0) {
    out[b] = v1 + osb[0];
    out[32 + b] = v2 + ocb[0];
  }
}

extern "C" void kernel_launch(void* const* d_in, const int* in_sizes, int n_in,
                              void* d_out, int out_size, void* d_ws, size_t ws_size,
                              hipStream_t stream) {
  const float* points  = (const float*)d_in[0];
  const float* grasp   = (const float*)d_in[1];
  const float* initp   = (const float*)d_in[2];
  const float* finalp  = (const float*)d_in[3];
  const int*   surf    = (const int*)d_in[4];
  const float* sa1_w0  = (const float*)d_in[5];
  const float* sa1_b0  = (const float*)d_in[6];
  const float* sa1_w1  = (const float*)d_in[7];
  const float* sa1_b1  = (const float*)d_in[8];
  const float* sa1_w2  = (const float*)d_in[9];
  const float* sa1_b2  = (const float*)d_in[10];
  const float* sa2_w0  = (const float*)d_in[11];
  const float* sa2_b0  = (const float*)d_in[12];
  const float* sa2_w1  = (const float*)d_in[13];
  const float* sa2_b1  = (const float*)d_in[14];
  const float* sa2_w2  = (const float*)d_in[15];
  const float* sa2_b2  = (const float*)d_in[16];
  const float* embi    = (const float*)d_in[17];
  const float* embf    = (const float*)d_in[18];
  const float* pe_w0   = (const float*)d_in[19];
  const float* pe_b0   = (const float*)d_in[20];
  const float* pe_w1   = (const float*)d_in[21];
  const float* pe_b1   = (const float*)d_in[22];
  const float* pe_w2   = (const float*)d_in[23];
  const float* pe_b2   = (const float*)d_in[24];
  const float* fu_w0   = (const float*)d_in[25];
  const float* fu_b0   = (const float*)d_in[26];
  const float* fu_w1   = (const float*)d_in[27];
  const float* fu_b1   = (const float*)d_in[28];
  const float* os_w    = (const float*)d_in[29];
  const float* os_b    = (const float*)d_in[30];
  const float* oc_w    = (const float*)d_in[31];
  const float* oc_b    = (const float*)d_in[32];

  char* ws = (char*)d_ws;
  // layout (bytes):
  int*    fidx    = (int*)(ws + 0);               //  65536
  float*  new_xyz = (float*)(ws + 65536);         // 196608
  int*    gidx    = (int*)(ws + 262144);          // 2097152
  float*  l1p     = (float*)(ws + 2359296);       // 8388608 (reused as h1t)
  float4* h0t4    = (float4*)(ws + 10747904);     // 8388608
  float*  pmax    = (float*)(ws + 19136512);      // 262144  -> end 19398656
  float4* h1t4    = (float4*)l1p;  // l1_points dead after k_sa2_l0
  const size_t base_end = 19398656;

  float* out = (float*)d_out;

  k_fps<<<32, 256, 0, stream>>>(points, fidx);
  k_ballq<<<4096, 256, 0, stream>>>(points, fidx, new_xyz, gidx);

  // SA1: split path with svT staged in ws (tiered by ws_size), else fused.
  const size_t NSAMP = 524288;  // 32*512*32
  int SC = 0;
  if (ws_size >= base_end + NSAMP * 256) SC = (int)NSAMP;       // +134.2 MB
  else if (ws_size >= base_end + (NSAMP / 4) * 256) SC = 131072;  // +33.5 MB
  if (SC > 0) {
    float4* svT = (float4*)(ws + base_end);
    const int nc = (int)(NSAMP / SC);
    for (int ci = 0; ci < nc; ++ci) {
      k_sa1a<<<SC / 256, 256, 0, stream>>>(points, new_xyz, gidx, sa1_w0,
                                           sa1_b0, sa1_w1, sa1_b1, svT,
                                           ci * SC, SC);
      k_sa1b<<<SC / 256, 256, 0, stream>>>(svT, sa1_w2, sa1_b2, l1p, ci * SC,
                                           SC);
    }
  } else {
    k_sa1_fused<<<2048, 256, 0, stream>>>(points, new_xyz, gidx, sa1_w0,
                                          sa1_b0, sa1_w1, sa1_b1, sa1_w2,
                                          sa1_b2, l1p);
  }

  k_sa2_l0<<<512, 256, 0, stream>>>(new_xyz, l1p, sa2_w0, sa2_b0, h0t4);
  k_sa2_l1<<<512, 256, 0, stream>>>(h0t4, sa2_w1, sa2_b1, h1t4);
  k_sa2_l2max<<<1024, 256, 0, stream>>>(h1t4, sa2_w2, sa2_b2, pmax);
  k_head<<<32, 64, 0, stream>>>(pmax, grasp, initp, finalp, surf, embi, embf,
                                pe_w0, pe_b0, pe_w1, pe_b1, pe_w2, pe_b2, fu_w0,
                                fu_b0, fu_w1, fu_b1, os_w, os_b, oc_w, oc_b, out);
}